// Round 9
// baseline (327.702 us; speedup 1.0000x reference)
//
#include <hip/hip_runtime.h>
#include <hip/hip_bf16.h>
#include <math.h>

typedef __hip_bfloat16 bf16;
typedef __attribute__((ext_vector_type(8))) short short8;
typedef __attribute__((ext_vector_type(4))) float floatx4;
typedef __attribute__((ext_vector_type(4))) unsigned uintx4;

#define GLDS16(g, l) __builtin_amdgcn_global_load_lds( \
    (const __attribute__((address_space(1))) void*)(g), \
    (__attribute__((address_space(3))) void*)(l), 16, 0, 0)

__device__ __forceinline__ bf16 f2bf(float v) { return __float2bfloat16(v); }

// pack two f32 -> one u32 of two bf16 (lo = a, hi = b)
__device__ __forceinline__ unsigned cvtpk(float a, float b) {
  unsigned r;
  asm volatile("v_cvt_pk_bf16_f32 %0, %1, %2" : "=v"(r) : "v"(a), "v"(b));
  return r;
}

// ---------------- weight convert + transpose: w[K][N] f32 -> wT[N][K] bf16
__global__ __launch_bounds__(256) void kconvT(const float* __restrict__ w,
                                              bf16* __restrict__ wT,
                                              int K, int N) {
  __shared__ float tile[32][33];
  const int n0 = blockIdx.x * 32, k0 = blockIdx.y * 32;
  const int tc = threadIdx.x & 31, tr = threadIdx.x >> 5;  // tr 0..7
#pragma unroll
  for (int p = 0; p < 4; p++)
    tile[tr + p * 8][tc] = w[(size_t)(k0 + tr + p * 8) * N + n0 + tc];
  __syncthreads();
#pragma unroll
  for (int p = 0; p < 4; p++)
    wT[(size_t)(n0 + tr + p * 8) * K + k0 + tc] = f2bf(tile[tc][tr + p * 8]);
}

// ---------------- LayerNorm: f32 [rows][768] -> bf16
__global__ __launch_bounds__(256) void kln(const float* __restrict__ x,
                                           const float* __restrict__ gw,
                                           const float* __restrict__ bw,
                                           bf16* __restrict__ out) {
  const int row = blockIdx.x, tid = threadIdx.x;
  const float* xr = x + (size_t)row * 768;
  float v0 = xr[tid], v1 = xr[tid + 256], v2 = xr[tid + 512];
  float s = v0 + v1 + v2;
  float s2 = v0 * v0 + v1 * v1 + v2 * v2;
#pragma unroll
  for (int off = 1; off < 64; off <<= 1) {
    s += __shfl_xor(s, off);
    s2 += __shfl_xor(s2, off);
  }
  __shared__ float red[8];
  const int wid = tid >> 6, lane = tid & 63;
  if (lane == 0) { red[wid] = s; red[4 + wid] = s2; }
  __syncthreads();
  s = red[0] + red[1] + red[2] + red[3];
  s2 = red[4] + red[5] + red[6] + red[7];
  const float mu = s * (1.f / 768.f);
  const float rst = rsqrtf(fmaxf(s2 * (1.f / 768.f) - mu * mu, 0.f) + 1e-5f);
  bf16* orow = out + (size_t)row * 768;
  orow[tid] = f2bf((v0 - mu) * rst * gw[tid] + bw[tid]);
  orow[tid + 256] = f2bf((v1 - mu) * rst * gw[tid + 256] + bw[tid + 256]);
  orow[tid + 512] = f2bf((v2 - mu) * rst * gw[tid + 512] + bw[tid + 512]);
}

// ---------------- V transpose: qkv[b*T+t][1536 + h*64 + d] -> VT[b][h][d][t]
__global__ __launch_bounds__(256) void kxpose(const bf16* __restrict__ qkv,
                                              bf16* __restrict__ VT) {
  const int T = 2048, C3 = 2304;
  const int t0 = blockIdx.x * 64, h = blockIdx.y, b = blockIdx.z;
  const int tid = threadIdx.x;
  __shared__ short tile[64][66];
  const bf16* src = qkv + (size_t)b * T * C3 + 1536 + h * 64;
  const int tr = tid >> 3, c = tid & 7;
#pragma unroll
  for (int p = 0; p < 2; p++) {
    short8 v = *(const short8*)(src + (size_t)(t0 + tr + p * 32) * C3 + c * 8);
    *(short8*)&tile[tr + p * 32][c * 8] = v;
  }
  __syncthreads();
  bf16* dst = VT + ((size_t)(b * 12 + h) * 64) * T + t0;
#pragma unroll
  for (int p = 0; p < 2; p++) {
    const int d = (tid >> 3) + p * 32, tc = tid & 7;
    short8 v;
#pragma unroll
    for (int j = 0; j < 8; j++) v[j] = tile[tc * 8 + j][d];
    *(short8*)(dst + (size_t)d * T + tc * 8) = v;
  }
}

// ---------------- GEMM: C[M,N] = A[M,K] * BT[N,K]^T, bf16 inputs, f32 accum
// EPI 0: +bias -> bf16   EPI 1: +bias+resid -> f32   EPI 2: +bias, GELU -> bf16
template <int BN, int EPI>
__global__ __launch_bounds__(256, 2) void kgemm(
    const bf16* __restrict__ A, const bf16* __restrict__ BT,
    const float* __restrict__ bias, const float* __restrict__ resid,
    bf16* __restrict__ outb, float* __restrict__ outf, int M, int N, int K) {
  __shared__ bf16 As[128 * 32];
  __shared__ bf16 Bs[BN * 32];
  const int tid = threadIdx.x;
  const int wid = tid >> 6, lane = tid & 63, g = lane >> 4, q = lane & 15;
  constexpr int FM = (BN == 128) ? 4 : 2;
  constexpr int FN = 4;
  constexpr int WM = (BN == 128) ? 64 : 32;
  const int wr = (BN == 128) ? (wid >> 1) : wid;
  const int wc = (BN == 128) ? (wid & 1) : 0;
  const int row0 = blockIdx.y * 128, col0 = blockIdx.x * BN;
  floatx4 acc[FM][FN] = {};
  const int r0 = tid >> 2;        // staging row (inst 0)
  const int c0 = (tid & 3) * 8;   // staging col
  const bf16* Ab = A + (size_t)row0 * K;
  const bf16* Bb = BT + (size_t)col0 * K;

  for (int k0 = 0; k0 < K; k0 += 32) {
    GLDS16(Ab + (size_t)r0 * K + k0 + c0, (char*)As + wid * 1024);
    GLDS16(Ab + (size_t)(r0 + 64) * K + k0 + c0, (char*)As + 4096 + wid * 1024);
    GLDS16(Bb + (size_t)r0 * K + k0 + c0, (char*)Bs + wid * 1024);
    if constexpr (BN == 128)
      GLDS16(Bb + (size_t)(r0 + 64) * K + k0 + c0, (char*)Bs + 4096 + wid * 1024);
    __syncthreads();
    short8 af[FM], bfr[FN];
#pragma unroll
    for (int m = 0; m < FM; m++)
      af[m] = *(const short8*)&As[(wr * WM + m * 16 + q) * 32 + g * 8];
#pragma unroll
    for (int n = 0; n < FN; n++)
      bfr[n] = *(const short8*)&Bs[(wc * 64 + n * 16 + q) * 32 + g * 8];
#pragma unroll
    for (int m = 0; m < FM; m++)
#pragma unroll
      for (int n = 0; n < FN; n++)
        acc[m][n] =
            __builtin_amdgcn_mfma_f32_16x16x32_bf16(af[m], bfr[n], acc[m][n], 0, 0, 0);
    __syncthreads();
  }

#pragma unroll
  for (int n = 0; n < FN; n++) {
    const int col = col0 + wc * 64 + n * 16 + q;
    const float bv = bias[col];
#pragma unroll
    for (int m = 0; m < FM; m++) {
      const int rowb = row0 + wr * WM + m * 16 + g * 4;
#pragma unroll
      for (int r = 0; r < 4; r++) {
        const size_t idx = (size_t)(rowb + r) * N + col;
        const float v = acc[m][n][r] + bv;
        if (EPI == 0) {
          outb[idx] = f2bf(v);
        } else if (EPI == 1) {
          outf[idx] = v + resid[idx];
        } else {
          const float t = tanhf(0.7978845608028654f * (v + 0.044715f * v * v * v));
          outb[idx] = f2bf(0.5f * v * (1.0f + t));
        }
      }
    }
  }
}

// ---------------- causal flash attention (real path, unchanged from R8)
__global__ __launch_bounds__(1024, 2) void kattn(const bf16* __restrict__ qkv,
                                                 const bf16* __restrict__ VT,
                                                 bf16* __restrict__ y) {
  const int T = 2048, C3 = 2304;
  const int tid = threadIdx.x;
  const int wid = tid >> 6, lane = tid & 63;
  const int g = lane >> 4, qi = lane & 15;
  const int w = wid & 3, gid = wid >> 2;   // w: q-subset, gid: kv-group

  const int bid = blockIdx.x;
  const int lb = (bid & 7) * 96 + (bid >> 3);
  const int qblk = 31 - (lb & 31);
  const int h = (lb >> 5) % 12, b = (lb >> 5) / 12;
  const int q0w = qblk * 64 + w * 16;
  const int qrow = q0w + qi;

  const bf16* Qb = qkv + (size_t)b * T * C3 + h * 64;
  const bf16* Kb = Qb + 768;
  const bf16* VTb = VT + (size_t)(b * 12 + h) * 64 * T;

  __shared__ __align__(16) char smem[52224];
  float* OM = (float*)smem;
  float* ML = (float*)(smem + 3 * 64 * 66 * 4);

  const int nt = qblk + 1;
  const int ntq = (nt + 3) >> 2;
  const int first = gid * ntq;
  const int last = min(nt, first + ntq);

  short8 qf[2];
#pragma unroll
  for (int s = 0; s < 2; s++)
    qf[s] = *(const short8*)(Qb + (size_t)qrow * C3 + s * 32 + g * 8);

  const int kvb = (qi >> 2) * 8 + (qi & 3);

  float m_run = -1e30f, l_run = 0.f;
  floatx4 o[4] = {};

  for (int tg = first; tg < last; tg++) {
    const int kv0 = tg * 64;
    short8 kf[8];
#pragma unroll
    for (int c = 0; c < 4; c++) {
      const int krow = kv0 + kvb + (c & 1) * 4 + (c >> 1) * 32;
#pragma unroll
      for (int s = 0; s < 2; s++)
        kf[c * 2 + s] = *(const short8*)(Kb + (size_t)krow * C3 + s * 32 + g * 8);
    }
    short8 vfr[8];
#pragma unroll
    for (int ks = 0; ks < 2; ks++)
#pragma unroll
      for (int n = 0; n < 4; n++)
        vfr[ks * 4 + n] =
            *(const short8*)(VTb + (size_t)(n * 16 + qi) * T + kv0 + ks * 32 + g * 8);

    floatx4 sacc[4] = {};
#pragma unroll
    for (int c = 0; c < 4; c++)
#pragma unroll
      for (int s = 0; s < 2; s++)
        sacc[c] =
            __builtin_amdgcn_mfma_f32_16x16x32_bf16(kf[c * 2 + s], qf[s], sacc[c], 0, 0, 0);

    if (kv0 + 63 > q0w) {
#pragma unroll
      for (int c = 0; c < 4; c++)
#pragma unroll
        for (int r = 0; r < 4; r++) {
          const int kv = kv0 + g * 8 + (c & 1) * 4 + r + (c >> 1) * 32;
          if (kv > qrow) sacc[c][r] = -1e30f;
        }
    }
    float mx = sacc[0][0];
#pragma unroll
    for (int c = 0; c < 4; c++)
#pragma unroll
      for (int r = 0; r < 4; r++) mx = fmaxf(mx, sacc[c][r]);
    mx = fmaxf(mx, __shfl_xor(mx, 16));
    mx = fmaxf(mx, __shfl_xor(mx, 32));
    mx *= 0.125f;
    const float mn = fmaxf(m_run, mx);
    const float al = __expf(m_run - mn);
    float ps = 0.f;
    unsigned pk[8];
#pragma unroll
    for (int c = 0; c < 4; c++) {
      float p0 = __expf(fmaf(sacc[c][0], 0.125f, -mn));
      float p1 = __expf(fmaf(sacc[c][1], 0.125f, -mn));
      float p2 = __expf(fmaf(sacc[c][2], 0.125f, -mn));
      float p3 = __expf(fmaf(sacc[c][3], 0.125f, -mn));
      ps += (p0 + p1) + (p2 + p3);
      pk[c * 2] = cvtpk(p0, p1);
      pk[c * 2 + 1] = cvtpk(p2, p3);
    }
    ps += __shfl_xor(ps, 16);
    ps += __shfl_xor(ps, 32);
    l_run = l_run * al + ps;
    m_run = mn;
#pragma unroll
    for (int n = 0; n < 4; n++) o[n] *= al;

#pragma unroll
    for (int ks = 0; ks < 2; ks++) {
      uintx4 pu;
      pu.x = pk[ks * 4 + 0];
      pu.y = pk[ks * 4 + 1];
      pu.z = pk[ks * 4 + 2];
      pu.w = pk[ks * 4 + 3];
      const short8 pf = __builtin_bit_cast(short8, pu);
#pragma unroll
      for (int n = 0; n < 4; n++)
        o[n] = __builtin_amdgcn_mfma_f32_16x16x32_bf16(vfr[ks * 4 + n], pf, o[n], 0, 0, 0);
    }
  }

  const int qlocal = w * 16 + qi;
  __syncthreads();
  if (gid > 0) {
    const int s = gid - 1;
    if (g == 0) { ML[s * 128 + qlocal] = m_run; ML[s * 128 + 64 + qlocal] = l_run; }
#pragma unroll
    for (int n = 0; n < 4; n++)
#pragma unroll
      for (int r = 0; r < 4; r++)
        OM[(size_t)(s * 64 + n * 16 + g * 4 + r) * 66 + qlocal] = o[n][r];
  }
  __syncthreads();
  if (gid == 0) {
    float ms[3], ls[3];
    float mn = m_run;
#pragma unroll
    for (int s = 0; s < 3; s++) {
      ms[s] = ML[s * 128 + qlocal];
      ls[s] = ML[s * 128 + 64 + qlocal];
      mn = fmaxf(mn, ms[s]);
    }
    const float a0 = __expf(m_run - mn);
    float as[3];
    float l = l_run * a0;
#pragma unroll
    for (int s = 0; s < 3; s++) { as[s] = __expf(ms[s] - mn); l += ls[s] * as[s]; }
    const float inv = 1.0f / l;
    bf16* yr = y + (size_t)(b * T + qrow) * 768 + h * 64;
#pragma unroll
    for (int n = 0; n < 4; n++) {
      float v[4];
#pragma unroll
      for (int r = 0; r < 4; r++) {
        float ov = o[n][r] * a0;
#pragma unroll
        for (int s = 0; s < 3; s++)
          ov += OM[(size_t)(s * 64 + n * 16 + g * 4 + r) * 66 + qlocal] * as[s];
        v[r] = ov * inv;
      }
      uint2 pr;
      pr.x = cvtpk(v[0], v[1]);
      pr.y = cvtpk(v[2], v[3]);
      *(uint2*)(yr + n * 16 + g * 4) = pr;
    }
  }
}

// ---------------- ABLATION PROBE: kattn with ALL K/V loads removed.
// Identical loop counts, MFMAs, softmax, merge, and writes (to scratch).
// kf/vfr come from registers (qf) so no VMEM in the loop; downstream stays
// live via the scratch store (no DCE). dur(probe) = kattn minus load cost.
__global__ __launch_bounds__(1024, 2) void kattn_noload(const bf16* __restrict__ qkv,
                                                        bf16* __restrict__ y) {
  const int T = 2048, C3 = 2304;
  const int tid = threadIdx.x;
  const int wid = tid >> 6, lane = tid & 63;
  const int g = lane >> 4, qi = lane & 15;
  const int w = wid & 3, gid = wid >> 2;

  const int bid = blockIdx.x;
  const int lb = (bid & 7) * 96 + (bid >> 3);
  const int qblk = 31 - (lb & 31);
  const int h = (lb >> 5) % 12, b = (lb >> 5) / 12;
  const int q0w = qblk * 64 + w * 16;
  const int qrow = q0w + qi;

  const bf16* Qb = qkv + (size_t)b * T * C3 + h * 64;

  __shared__ __align__(16) char smem[52224];
  float* OM = (float*)smem;
  float* ML = (float*)(smem + 3 * 64 * 66 * 4);

  const int nt = qblk + 1;
  const int ntq = (nt + 3) >> 2;
  const int first = gid * ntq;
  const int last = min(nt, first + ntq);

  short8 qf[2];
#pragma unroll
  for (int s = 0; s < 2; s++)
    qf[s] = *(const short8*)(Qb + (size_t)qrow * C3 + s * 32 + g * 8);

  float m_run = -1e30f, l_run = 0.f;
  floatx4 o[4] = {};

  for (int tg = first; tg < last; tg++) {
    const int kv0 = tg * 64;

    floatx4 sacc[4] = {};
#pragma unroll
    for (int c = 0; c < 4; c++)
#pragma unroll
      for (int s = 0; s < 2; s++)
        sacc[c] =
            __builtin_amdgcn_mfma_f32_16x16x32_bf16(qf[s], qf[s], sacc[c], 0, 0, 0);

    if (kv0 + 63 > q0w) {
#pragma unroll
      for (int c = 0; c < 4; c++)
#pragma unroll
        for (int r = 0; r < 4; r++) {
          const int kv = kv0 + g * 8 + (c & 1) * 4 + r + (c >> 1) * 32;
          if (kv > qrow) sacc[c][r] = -1e30f;
        }
    }
    float mx = sacc[0][0];
#pragma unroll
    for (int c = 0; c < 4; c++)
#pragma unroll
      for (int r = 0; r < 4; r++) mx = fmaxf(mx, sacc[c][r]);
    mx = fmaxf(mx, __shfl_xor(mx, 16));
    mx = fmaxf(mx, __shfl_xor(mx, 32));
    mx *= 0.125f;
    const float mn = fmaxf(m_run, mx);
    const float al = __expf(m_run - mn);
    float ps = 0.f;
    unsigned pk[8];
#pragma unroll
    for (int c = 0; c < 4; c++) {
      float p0 = __expf(fmaf(sacc[c][0], 0.125f, -mn));
      float p1 = __expf(fmaf(sacc[c][1], 0.125f, -mn));
      float p2 = __expf(fmaf(sacc[c][2], 0.125f, -mn));
      float p3 = __expf(fmaf(sacc[c][3], 0.125f, -mn));
      ps += (p0 + p1) + (p2 + p3);
      pk[c * 2] = cvtpk(p0, p1);
      pk[c * 2 + 1] = cvtpk(p2, p3);
    }
    ps += __shfl_xor(ps, 16);
    ps += __shfl_xor(ps, 32);
    l_run = l_run * al + ps;
    m_run = mn;
#pragma unroll
    for (int n = 0; n < 4; n++) o[n] *= al;

#pragma unroll
    for (int ks = 0; ks < 2; ks++) {
      uintx4 pu;
      pu.x = pk[ks * 4 + 0];
      pu.y = pk[ks * 4 + 1];
      pu.z = pk[ks * 4 + 2];
      pu.w = pk[ks * 4 + 3];
      const short8 pf = __builtin_bit_cast(short8, pu);
#pragma unroll
      for (int n = 0; n < 4; n++)
        o[n] = __builtin_amdgcn_mfma_f32_16x16x32_bf16(qf[ks & 1], pf, o[n], 0, 0, 0);
    }
  }

  const int qlocal = w * 16 + qi;
  __syncthreads();
  if (gid > 0) {
    const int s = gid - 1;
    if (g == 0) { ML[s * 128 + qlocal] = m_run; ML[s * 128 + 64 + qlocal] = l_run; }
#pragma unroll
    for (int n = 0; n < 4; n++)
#pragma unroll
      for (int r = 0; r < 4; r++)
        OM[(size_t)(s * 64 + n * 16 + g * 4 + r) * 66 + qlocal] = o[n][r];
  }
  __syncthreads();
  if (gid == 0) {
    float ms[3], ls[3];
    float mn = m_run;
#pragma unroll
    for (int s = 0; s < 3; s++) {
      ms[s] = ML[s * 128 + qlocal];
      ls[s] = ML[s * 128 + 64 + qlocal];
      mn = fmaxf(mn, ms[s]);
    }
    const float a0 = __expf(m_run - mn);
    float as[3];
    float l = l_run * a0;
#pragma unroll
    for (int s = 0; s < 3; s++) { as[s] = __expf(ms[s] - mn); l += ls[s] * as[s]; }
    const float inv = 1.0f / l;
    bf16* yr = y + (size_t)(b * T + qrow) * 768 + h * 64;
#pragma unroll
    for (int n = 0; n < 4; n++) {
      float v[4];
#pragma unroll
      for (int r = 0; r < 4; r++) {
        float ov = o[n][r] * a0;
#pragma unroll
        for (int s = 0; s < 3; s++)
          ov += OM[(size_t)(s * 64 + n * 16 + g * 4 + r) * 66 + qlocal] * as[s];
        v[r] = ov * inv;
      }
      uint2 pr;
      pr.x = cvtpk(v[0], v[1]);
      pr.y = cvtpk(v[2], v[3]);
      *(uint2*)(yr + n * 16 + g * 4) = pr;
    }
  }
}

// ---------------- host side
extern "C" void kernel_launch(void* const* d_in, const int* in_sizes, int n_in,
                              void* d_out, int out_size, void* d_ws, size_t ws_size,
                              hipStream_t stream) {
  const float* x      = (const float*)d_in[0];
  const float* ln1_g  = (const float*)d_in[1];
  const float* ln1_b  = (const float*)d_in[2];
  const float* w_attn = (const float*)d_in[3];
  const float* b_attn = (const float*)d_in[4];
  const float* w_proj = (const float*)d_in[5];
  const float* b_proj = (const float*)d_in[6];
  const float* ln2_g  = (const float*)d_in[7];
  const float* ln2_b  = (const float*)d_in[8];
  const float* w_fc   = (const float*)d_in[9];
  const float* b_fc   = (const float*)d_in[10];
  const float* w_fc2  = (const float*)d_in[11];
  const float* b_fc2  = (const float*)d_in[12];
  float* out = (float*)d_out;

  const int M = 4096;  // B*T
  char* p = (char*)d_ws;
  bf16* wT_attn = (bf16*)p; p += (size_t)2304 * 768 * 2;
  bf16* wT_proj = (bf16*)p; p += (size_t)768 * 768 * 2;
  bf16* wT_fc   = (bf16*)p; p += (size_t)3072 * 768 * 2;
  bf16* wT_fc2  = (bf16*)p; p += (size_t)768 * 3072 * 2;
  bf16* h       = (bf16*)p; p += (size_t)M * 768 * 2;
  bf16* qkv     = (bf16*)p;
  bf16* yb      = (bf16*)(p + (size_t)M * 2304 * 2);
  bf16* act     = qkv;      p += (size_t)M * 2304 * 2 + (size_t)M * 768 * 2;
  float* x1     = (float*)p;
  bf16* VT      = (bf16*)p;  // aliases x1: VT dead before x1 is written

  // weights -> bf16 transposed
  kconvT<<<dim3(2304 / 32, 768 / 32), 256, 0, stream>>>(w_attn, wT_attn, 768, 2304);
  kconvT<<<dim3(768 / 32, 768 / 32), 256, 0, stream>>>(w_proj, wT_proj, 768, 768);
  kconvT<<<dim3(3072 / 32, 768 / 32), 256, 0, stream>>>(w_fc, wT_fc, 768, 3072);
  kconvT<<<dim3(768 / 32, 3072 / 32), 256, 0, stream>>>(w_fc2, wT_fc2, 3072, 768);

  // attention branch
  kln<<<M, 256, 0, stream>>>(x, ln1_g, ln1_b, h);
  kgemm<128, 0><<<dim3(2304 / 128, M / 128), 256, 0, stream>>>(
      h, wT_attn, b_attn, nullptr, qkv, nullptr, M, 2304, 768);
  kxpose<<<dim3(32, 12, 2), 256, 0, stream>>>(qkv, VT);
  kattn<<<dim3(768), 1024, 0, stream>>>(qkv, VT, yb);
  kgemm<64, 1><<<dim3(768 / 64, M / 128), 256, 0, stream>>>(
      yb, wT_proj, b_proj, x, nullptr, x1, M, 768, 768);

  // MLP branch
  kln<<<M, 256, 0, stream>>>(x1, ln2_g, ln2_b, h);
  kgemm<128, 2><<<dim3(3072 / 128, M / 128), 256, 0, stream>>>(
      h, wT_fc, b_fc, nullptr, act, nullptr, M, 3072, 768);
  kgemm<64, 1><<<dim3(768 / 64, M / 128), 256, 0, stream>>>(
      act, wT_fc2, b_fc2, x1, nullptr, out, M, 768, 3072);

  // ABLATION PROBE (last; writes into h, which is dead now; reads only qkv)
  kattn_noload<<<dim3(768), 1024, 0, stream>>>(qkv, h);
}

// Round 10
// 307.277 us; speedup vs baseline: 1.0665x; 1.0665x over previous
//
#include <hip/hip_runtime.h>
#include <hip/hip_bf16.h>
#include <math.h>

typedef __hip_bfloat16 bf16;
typedef __attribute__((ext_vector_type(8))) short short8;
typedef __attribute__((ext_vector_type(4))) float floatx4;
typedef __attribute__((ext_vector_type(4))) unsigned uintx4;

#define GLDS16(g, l) __builtin_amdgcn_global_load_lds( \
    (const __attribute__((address_space(1))) void*)(g), \
    (__attribute__((address_space(3))) void*)(l), 16, 0, 0)

__device__ __forceinline__ bf16 f2bf(float v) { return __float2bfloat16(v); }

// pack two f32 -> one u32 of two bf16 (lo = a, hi = b)
__device__ __forceinline__ unsigned cvtpk(float a, float b) {
  unsigned r;
  asm volatile("v_cvt_pk_bf16_f32 %0, %1, %2" : "=v"(r) : "v"(a), "v"(b));
  return r;
}

// un-sinkable 16B global load: SGPR base + 32-bit byte voffset.
// asm volatile => compiler cannot sink it to the use site; issuing a batch
// of these keeps all of them in flight under ONE s_waitcnt.
__device__ __forceinline__ short8 gload16(const bf16* __restrict__ base,
                                          unsigned byteoff) {
  short8 r;
  asm volatile("global_load_dwordx4 %0, %1, %2"
               : "=&v"(r) : "v"(byteoff), "s"(base));
  return r;
}

// ---------------- weight convert + transpose: w[K][N] f32 -> wT[N][K] bf16
__global__ __launch_bounds__(256) void kconvT(const float* __restrict__ w,
                                              bf16* __restrict__ wT,
                                              int K, int N) {
  __shared__ float tile[32][33];
  const int n0 = blockIdx.x * 32, k0 = blockIdx.y * 32;
  const int tc = threadIdx.x & 31, tr = threadIdx.x >> 5;  // tr 0..7
#pragma unroll
  for (int p = 0; p < 4; p++)
    tile[tr + p * 8][tc] = w[(size_t)(k0 + tr + p * 8) * N + n0 + tc];
  __syncthreads();
#pragma unroll
  for (int p = 0; p < 4; p++)
    wT[(size_t)(n0 + tr + p * 8) * K + k0 + tc] = f2bf(tile[tc][tr + p * 8]);
}

// ---------------- LayerNorm: f32 [rows][768] -> bf16
__global__ __launch_bounds__(256) void kln(const float* __restrict__ x,
                                           const float* __restrict__ gw,
                                           const float* __restrict__ bw,
                                           bf16* __restrict__ out) {
  const int row = blockIdx.x, tid = threadIdx.x;
  const float* xr = x + (size_t)row * 768;
  float v0 = xr[tid], v1 = xr[tid + 256], v2 = xr[tid + 512];
  float s = v0 + v1 + v2;
  float s2 = v0 * v0 + v1 * v1 + v2 * v2;
#pragma unroll
  for (int off = 1; off < 64; off <<= 1) {
    s += __shfl_xor(s, off);
    s2 += __shfl_xor(s2, off);
  }
  __shared__ float red[8];
  const int wid = tid >> 6, lane = tid & 63;
  if (lane == 0) { red[wid] = s; red[4 + wid] = s2; }
  __syncthreads();
  s = red[0] + red[1] + red[2] + red[3];
  s2 = red[4] + red[5] + red[6] + red[7];
  const float mu = s * (1.f / 768.f);
  const float rst = rsqrtf(fmaxf(s2 * (1.f / 768.f) - mu * mu, 0.f) + 1e-5f);
  bf16* orow = out + (size_t)row * 768;
  orow[tid] = f2bf((v0 - mu) * rst * gw[tid] + bw[tid]);
  orow[tid + 256] = f2bf((v1 - mu) * rst * gw[tid + 256] + bw[tid + 256]);
  orow[tid + 512] = f2bf((v2 - mu) * rst * gw[tid + 512] + bw[tid + 512]);
}

// ---------------- V transpose: qkv[b*T+t][1536 + h*64 + d] -> VT[b][h][d][t]
__global__ __launch_bounds__(256) void kxpose(const bf16* __restrict__ qkv,
                                              bf16* __restrict__ VT) {
  const int T = 2048, C3 = 2304;
  const int t0 = blockIdx.x * 64, h = blockIdx.y, b = blockIdx.z;
  const int tid = threadIdx.x;
  __shared__ short tile[64][66];
  const bf16* src = qkv + (size_t)b * T * C3 + 1536 + h * 64;
  const int tr = tid >> 3, c = tid & 7;
#pragma unroll
  for (int p = 0; p < 2; p++) {
    short8 v = *(const short8*)(src + (size_t)(t0 + tr + p * 32) * C3 + c * 8);
    *(short8*)&tile[tr + p * 32][c * 8] = v;
  }
  __syncthreads();
  bf16* dst = VT + ((size_t)(b * 12 + h) * 64) * T + t0;
#pragma unroll
  for (int p = 0; p < 2; p++) {
    const int d = (tid >> 3) + p * 32, tc = tid & 7;
    short8 v;
#pragma unroll
    for (int j = 0; j < 8; j++) v[j] = tile[tc * 8 + j][d];
    *(short8*)(dst + (size_t)d * T + tc * 8) = v;
  }
}

// ---------------- GEMM: C[M,N] = A[M,K] * BT[N,K]^T, bf16 inputs, f32 accum
// EPI 0: +bias -> bf16   EPI 1: +bias+resid -> f32   EPI 2: +bias, GELU -> bf16
template <int BN, int EPI>
__global__ __launch_bounds__(256, 2) void kgemm(
    const bf16* __restrict__ A, const bf16* __restrict__ BT,
    const float* __restrict__ bias, const float* __restrict__ resid,
    bf16* __restrict__ outb, float* __restrict__ outf, int M, int N, int K) {
  __shared__ bf16 As[128 * 32];
  __shared__ bf16 Bs[BN * 32];
  const int tid = threadIdx.x;
  const int wid = tid >> 6, lane = tid & 63, g = lane >> 4, q = lane & 15;
  constexpr int FM = (BN == 128) ? 4 : 2;
  constexpr int FN = 4;
  constexpr int WM = (BN == 128) ? 64 : 32;
  const int wr = (BN == 128) ? (wid >> 1) : wid;
  const int wc = (BN == 128) ? (wid & 1) : 0;
  const int row0 = blockIdx.y * 128, col0 = blockIdx.x * BN;
  floatx4 acc[FM][FN] = {};
  const int r0 = tid >> 2;        // staging row (inst 0)
  const int c0 = (tid & 3) * 8;   // staging col
  const bf16* Ab = A + (size_t)row0 * K;
  const bf16* Bb = BT + (size_t)col0 * K;

  for (int k0 = 0; k0 < K; k0 += 32) {
    GLDS16(Ab + (size_t)r0 * K + k0 + c0, (char*)As + wid * 1024);
    GLDS16(Ab + (size_t)(r0 + 64) * K + k0 + c0, (char*)As + 4096 + wid * 1024);
    GLDS16(Bb + (size_t)r0 * K + k0 + c0, (char*)Bs + wid * 1024);
    if constexpr (BN == 128)
      GLDS16(Bb + (size_t)(r0 + 64) * K + k0 + c0, (char*)Bs + 4096 + wid * 1024);
    __syncthreads();
    short8 af[FM], bfr[FN];
#pragma unroll
    for (int m = 0; m < FM; m++)
      af[m] = *(const short8*)&As[(wr * WM + m * 16 + q) * 32 + g * 8];
#pragma unroll
    for (int n = 0; n < FN; n++)
      bfr[n] = *(const short8*)&Bs[(wc * 64 + n * 16 + q) * 32 + g * 8];
#pragma unroll
    for (int m = 0; m < FM; m++)
#pragma unroll
      for (int n = 0; n < FN; n++)
        acc[m][n] =
            __builtin_amdgcn_mfma_f32_16x16x32_bf16(af[m], bfr[n], acc[m][n], 0, 0, 0);
    __syncthreads();
  }

#pragma unroll
  for (int n = 0; n < FN; n++) {
    const int col = col0 + wc * 64 + n * 16 + q;
    const float bv = bias[col];
#pragma unroll
    for (int m = 0; m < FM; m++) {
      const int rowb = row0 + wr * WM + m * 16 + g * 4;
#pragma unroll
      for (int r = 0; r < 4; r++) {
        const size_t idx = (size_t)(rowb + r) * N + col;
        const float v = acc[m][n][r] + bv;
        if (EPI == 0) {
          outb[idx] = f2bf(v);
        } else if (EPI == 1) {
          outf[idx] = v + resid[idx];
        } else {
          const float t = tanhf(0.7978845608028654f * (v + 0.044715f * v * v * v));
          outb[idx] = f2bf(0.5f * v * (1.0f + t));
        }
      }
    }
  }
}

// ---------------- causal flash attention v8: asm-batched K/V loads.
// R9 ablation: noload probe = 21us vs 132us real -> ~111us is load cost; the
// compiler sinks HIP loads to uses (VGPR stayed 60), serializing ~16 L3-ish
// latencies per tile. Fix: issue all 16 fragment loads as asm volatile
// global_load_dwordx4 (un-sinkable, distinct VGPRs), then ONE
// s_waitcnt vmcnt(0) + sched_barrier(0) (rule #18) before compute.
__global__ __launch_bounds__(1024, 2) void kattn(const bf16* __restrict__ qkv,
                                                 const bf16* __restrict__ VT,
                                                 bf16* __restrict__ y) {
  const int T = 2048, C3 = 2304;
  const int tid = threadIdx.x;
  const int wid = tid >> 6, lane = tid & 63;
  const int g = lane >> 4, qi = lane & 15;
  const int w = wid & 3, gid = wid >> 2;   // w: q-subset, gid: kv-group

  const int bid = blockIdx.x;
  const int lb = (bid & 7) * 96 + (bid >> 3);
  const int qblk = 31 - (lb & 31);
  const int h = (lb >> 5) % 12, b = (lb >> 5) / 12;
  const int q0w = qblk * 64 + w * 16;
  const int qrow = q0w + qi;

  const bf16* Qb = qkv + (size_t)b * T * C3 + h * 64;
  const bf16* Kb = Qb + 768;
  const bf16* VTb = VT + (size_t)(b * 12 + h) * 64 * T;

  __shared__ __align__(16) char smem[52224];
  float* OM = (float*)smem;
  float* ML = (float*)(smem + 3 * 64 * 66 * 4);

  const int nt = qblk + 1;
  const int ntq = (nt + 3) >> 2;
  const int first = gid * ntq;
  const int last = min(nt, first + ntq);

  short8 qf[2];
#pragma unroll
  for (int s = 0; s < 2; s++)
    qf[s] = *(const short8*)(Qb + (size_t)qrow * C3 + s * 32 + g * 8);

  const int kvb = (qi >> 2) * 8 + (qi & 3);
  // byte offsets (uniform parts): K row stride 4608 B, VT row stride 4096 B
  const unsigned kcol = (unsigned)(g * 16);           // + s*64
  const unsigned vbase = (unsigned)((qi * T + g * 8) * 2);  // + n*16*T*2 + (kv0+ks*32)*2

  float m_run = -1e30f, l_run = 0.f;
  floatx4 o[4] = {};

  for (int tg = first; tg < last; tg++) {
    const int kv0 = tg * 64;

    // ---- issue all 16 loads (asm volatile: cannot be sunk) ----
    short8 kf[8], vfr[8];
#pragma unroll
    for (int c = 0; c < 4; c++) {
      const unsigned krowb =
          (unsigned)((kv0 + kvb + (c & 1) * 4 + (c >> 1) * 32) * 4608);
#pragma unroll
      for (int s = 0; s < 2; s++)
        kf[c * 2 + s] = gload16(Kb, krowb + kcol + (unsigned)(s * 64));
    }
#pragma unroll
    for (int ks = 0; ks < 2; ks++)
#pragma unroll
      for (int n = 0; n < 4; n++)
        vfr[ks * 4 + n] = gload16(
            VTb, vbase + (unsigned)(n * 16 * T * 2 + (kv0 + ks * 32) * 2));
    asm volatile("s_waitcnt vmcnt(0)");
    __builtin_amdgcn_sched_barrier(0);

    // S^T = K Q^T : sacc[c] col=q, row(g*4+r) -> kv = g*8+(c&1)*4+r+(c>>1)*32
    floatx4 sacc[4] = {};
#pragma unroll
    for (int c = 0; c < 4; c++)
#pragma unroll
      for (int s = 0; s < 2; s++)
        sacc[c] =
            __builtin_amdgcn_mfma_f32_16x16x32_bf16(kf[c * 2 + s], qf[s], sacc[c], 0, 0, 0);

    if (kv0 + 63 > q0w) {
#pragma unroll
      for (int c = 0; c < 4; c++)
#pragma unroll
        for (int r = 0; r < 4; r++) {
          const int kv = kv0 + g * 8 + (c & 1) * 4 + r + (c >> 1) * 32;
          if (kv > qrow) sacc[c][r] = -1e30f;
        }
    }
    float mx = sacc[0][0];
#pragma unroll
    for (int c = 0; c < 4; c++)
#pragma unroll
      for (int r = 0; r < 4; r++) mx = fmaxf(mx, sacc[c][r]);
    mx = fmaxf(mx, __shfl_xor(mx, 16));
    mx = fmaxf(mx, __shfl_xor(mx, 32));
    mx *= 0.125f;
    const float mn = fmaxf(m_run, mx);
    const float al = __expf(m_run - mn);
    float ps = 0.f;
    unsigned pk[8];
#pragma unroll
    for (int c = 0; c < 4; c++) {
      float p0 = __expf(fmaf(sacc[c][0], 0.125f, -mn));
      float p1 = __expf(fmaf(sacc[c][1], 0.125f, -mn));
      float p2 = __expf(fmaf(sacc[c][2], 0.125f, -mn));
      float p3 = __expf(fmaf(sacc[c][3], 0.125f, -mn));
      ps += (p0 + p1) + (p2 + p3);
      pk[c * 2] = cvtpk(p0, p1);
      pk[c * 2 + 1] = cvtpk(p2, p3);
    }
    ps += __shfl_xor(ps, 16);
    ps += __shfl_xor(ps, 32);
    l_run = l_run * al + ps;
    m_run = mn;
#pragma unroll
    for (int n = 0; n < 4; n++) o[n] *= al;

#pragma unroll
    for (int ks = 0; ks < 2; ks++) {
      uintx4 pu;
      pu.x = pk[ks * 4 + 0];
      pu.y = pk[ks * 4 + 1];
      pu.z = pk[ks * 4 + 2];
      pu.w = pk[ks * 4 + 3];
      const short8 pf = __builtin_bit_cast(short8, pu);
#pragma unroll
      for (int n = 0; n < 4; n++)
        o[n] = __builtin_amdgcn_mfma_f32_16x16x32_bf16(vfr[ks * 4 + n], pf, o[n], 0, 0, 0);
    }
  }

  const int qlocal = w * 16 + qi;
  __syncthreads();
  if (gid > 0) {
    const int s = gid - 1;
    if (g == 0) { ML[s * 128 + qlocal] = m_run; ML[s * 128 + 64 + qlocal] = l_run; }
#pragma unroll
    for (int n = 0; n < 4; n++)
#pragma unroll
      for (int r = 0; r < 4; r++)
        OM[(size_t)(s * 64 + n * 16 + g * 4 + r) * 66 + qlocal] = o[n][r];
  }
  __syncthreads();
  if (gid == 0) {
    float ms[3], ls[3];
    float mn = m_run;
#pragma unroll
    for (int s = 0; s < 3; s++) {
      ms[s] = ML[s * 128 + qlocal];
      ls[s] = ML[s * 128 + 64 + qlocal];
      mn = fmaxf(mn, ms[s]);
    }
    const float a0 = __expf(m_run - mn);
    float as[3];
    float l = l_run * a0;
#pragma unroll
    for (int s = 0; s < 3; s++) { as[s] = __expf(ms[s] - mn); l += ls[s] * as[s]; }
    const float inv = 1.0f / l;
    bf16* yr = y + (size_t)(b * T + qrow) * 768 + h * 64;
#pragma unroll
    for (int n = 0; n < 4; n++) {
      float v[4];
#pragma unroll
      for (int r = 0; r < 4; r++) {
        float ov = o[n][r] * a0;
#pragma unroll
        for (int s = 0; s < 3; s++)
          ov += OM[(size_t)(s * 64 + n * 16 + g * 4 + r) * 66 + qlocal] * as[s];
        v[r] = ov * inv;
      }
      uint2 pr;
      pr.x = cvtpk(v[0], v[1]);
      pr.y = cvtpk(v[2], v[3]);
      *(uint2*)(yr + n * 16 + g * 4) = pr;
    }
  }
}

// ---------------- host side
extern "C" void kernel_launch(void* const* d_in, const int* in_sizes, int n_in,
                              void* d_out, int out_size, void* d_ws, size_t ws_size,
                              hipStream_t stream) {
  const float* x      = (const float*)d_in[0];
  const float* ln1_g  = (const float*)d_in[1];
  const float* ln1_b  = (const float*)d_in[2];
  const float* w_attn = (const float*)d_in[3];
  const float* b_attn = (const float*)d_in[4];
  const float* w_proj = (const float*)d_in[5];
  const float* b_proj = (const float*)d_in[6];
  const float* ln2_g  = (const float*)d_in[7];
  const float* ln2_b  = (const float*)d_in[8];
  const float* w_fc   = (const float*)d_in[9];
  const float* b_fc   = (const float*)d_in[10];
  const float* w_fc2  = (const float*)d_in[11];
  const float* b_fc2  = (const float*)d_in[12];
  float* out = (float*)d_out;

  const int M = 4096;  // B*T
  char* p = (char*)d_ws;
  bf16* wT_attn = (bf16*)p; p += (size_t)2304 * 768 * 2;
  bf16* wT_proj = (bf16*)p; p += (size_t)768 * 768 * 2;
  bf16* wT_fc   = (bf16*)p; p += (size_t)3072 * 768 * 2;
  bf16* wT_fc2  = (bf16*)p; p += (size_t)768 * 3072 * 2;
  bf16* h       = (bf16*)p; p += (size_t)M * 768 * 2;
  bf16* qkv     = (bf16*)p;
  bf16* yb      = (bf16*)(p + (size_t)M * 2304 * 2);
  bf16* act     = qkv;      p += (size_t)M * 2304 * 2 + (size_t)M * 768 * 2;
  float* x1     = (float*)p;
  bf16* VT      = (bf16*)p;  // aliases x1: VT dead before x1 is written

  // weights -> bf16 transposed
  kconvT<<<dim3(2304 / 32, 768 / 32), 256, 0, stream>>>(w_attn, wT_attn, 768, 2304);
  kconvT<<<dim3(768 / 32, 768 / 32), 256, 0, stream>>>(w_proj, wT_proj, 768, 768);
  kconvT<<<dim3(3072 / 32, 768 / 32), 256, 0, stream>>>(w_fc, wT_fc, 768, 3072);
  kconvT<<<dim3(768 / 32, 3072 / 32), 256, 0, stream>>>(w_fc2, wT_fc2, 3072, 768);

  // attention branch
  kln<<<M, 256, 0, stream>>>(x, ln1_g, ln1_b, h);
  kgemm<128, 0><<<dim3(2304 / 128, M / 128), 256, 0, stream>>>(
      h, wT_attn, b_attn, nullptr, qkv, nullptr, M, 2304, 768);
  kxpose<<<dim3(32, 12, 2), 256, 0, stream>>>(qkv, VT);
  kattn<<<dim3(768), 1024, 0, stream>>>(qkv, VT, yb);
  kgemm<64, 1><<<dim3(768 / 64, M / 128), 256, 0, stream>>>(
      yb, wT_proj, b_proj, x, nullptr, x1, M, 768, 768);

  // MLP branch
  kln<<<M, 256, 0, stream>>>(x1, ln2_g, ln2_b, h);
  kgemm<128, 2><<<dim3(3072 / 128, M / 128), 256, 0, stream>>>(
      h, wT_fc, b_fc, nullptr, act, nullptr, M, 3072, 768);
  kgemm<64, 1><<<dim3(768 / 64, M / 128), 256, 0, stream>>>(
      act, wT_fc2, b_fc2, x1, nullptr, out, M, 768, 3072);
}

// Round 11
// 224.666 us; speedup vs baseline: 1.4586x; 1.3677x over previous
//
#include <hip/hip_runtime.h>
#include <hip/hip_bf16.h>
#include <math.h>

typedef __hip_bfloat16 bf16;
typedef __attribute__((ext_vector_type(8))) short short8;
typedef __attribute__((ext_vector_type(4))) float floatx4;
typedef __attribute__((ext_vector_type(4))) unsigned uintx4;

#define GLDS16(g, l) __builtin_amdgcn_global_load_lds( \
    (const __attribute__((address_space(1))) void*)(g), \
    (__attribute__((address_space(3))) void*)(l), 16, 0, 0)

__device__ __forceinline__ bf16 f2bf(float v) { return __float2bfloat16(v); }

// pack two f32 -> one u32 of two bf16 (lo = a, hi = b)
__device__ __forceinline__ unsigned cvtpk(float a, float b) {
  unsigned r;
  asm volatile("v_cvt_pk_bf16_f32 %0, %1, %2" : "=v"(r) : "v"(a), "v"(b));
  return r;
}

// ---------------- weight convert + transpose: w[K][N] f32 -> wT[N][K] bf16
__global__ __launch_bounds__(256) void kconvT(const float* __restrict__ w,
                                              bf16* __restrict__ wT,
                                              int K, int N) {
  __shared__ float tile[32][33];
  const int n0 = blockIdx.x * 32, k0 = blockIdx.y * 32;
  const int tc = threadIdx.x & 31, tr = threadIdx.x >> 5;  // tr 0..7
#pragma unroll
  for (int p = 0; p < 4; p++)
    tile[tr + p * 8][tc] = w[(size_t)(k0 + tr + p * 8) * N + n0 + tc];
  __syncthreads();
#pragma unroll
  for (int p = 0; p < 4; p++)
    wT[(size_t)(n0 + tr + p * 8) * K + k0 + tc] = f2bf(tile[tc][tr + p * 8]);
}

// ---------------- LayerNorm: f32 [rows][768] -> bf16
__global__ __launch_bounds__(256) void kln(const float* __restrict__ x,
                                           const float* __restrict__ gw,
                                           const float* __restrict__ bw,
                                           bf16* __restrict__ out) {
  const int row = blockIdx.x, tid = threadIdx.x;
  const float* xr = x + (size_t)row * 768;
  float v0 = xr[tid], v1 = xr[tid + 256], v2 = xr[tid + 512];
  float s = v0 + v1 + v2;
  float s2 = v0 * v0 + v1 * v1 + v2 * v2;
#pragma unroll
  for (int off = 1; off < 64; off <<= 1) {
    s += __shfl_xor(s, off);
    s2 += __shfl_xor(s2, off);
  }
  __shared__ float red[8];
  const int wid = tid >> 6, lane = tid & 63;
  if (lane == 0) { red[wid] = s; red[4 + wid] = s2; }
  __syncthreads();
  s = red[0] + red[1] + red[2] + red[3];
  s2 = red[4] + red[5] + red[6] + red[7];
  const float mu = s * (1.f / 768.f);
  const float rst = rsqrtf(fmaxf(s2 * (1.f / 768.f) - mu * mu, 0.f) + 1e-5f);
  bf16* orow = out + (size_t)row * 768;
  orow[tid] = f2bf((v0 - mu) * rst * gw[tid] + bw[tid]);
  orow[tid + 256] = f2bf((v1 - mu) * rst * gw[tid + 256] + bw[tid + 256]);
  orow[tid + 512] = f2bf((v2 - mu) * rst * gw[tid + 512] + bw[tid + 512]);
}

// ---------------- V transpose: qkv[b*T+t][1536 + h*64 + d] -> VT[b][h][d][t]
__global__ __launch_bounds__(256) void kxpose(const bf16* __restrict__ qkv,
                                              bf16* __restrict__ VT) {
  const int T = 2048, C3 = 2304;
  const int t0 = blockIdx.x * 64, h = blockIdx.y, b = blockIdx.z;
  const int tid = threadIdx.x;
  __shared__ short tile[64][66];
  const bf16* src = qkv + (size_t)b * T * C3 + 1536 + h * 64;
  const int tr = tid >> 3, c = tid & 7;
#pragma unroll
  for (int p = 0; p < 2; p++) {
    short8 v = *(const short8*)(src + (size_t)(t0 + tr + p * 32) * C3 + c * 8);
    *(short8*)&tile[tr + p * 32][c * 8] = v;
  }
  __syncthreads();
  bf16* dst = VT + ((size_t)(b * 12 + h) * 64) * T + t0;
#pragma unroll
  for (int p = 0; p < 2; p++) {
    const int d = (tid >> 3) + p * 32, tc = tid & 7;
    short8 v;
#pragma unroll
    for (int j = 0; j < 8; j++) v[j] = tile[tc * 8 + j][d];
    *(short8*)(dst + (size_t)d * T + tc * 8) = v;
  }
}

// ---------------- GEMM: C[M,N] = A[M,K] * BT[N,K]^T, bf16 inputs, f32 accum
// EPI 0: +bias -> bf16   EPI 1: +bias+resid -> f32   EPI 2: +bias, GELU -> bf16
template <int BN, int EPI>
__global__ __launch_bounds__(256, 2) void kgemm(
    const bf16* __restrict__ A, const bf16* __restrict__ BT,
    const float* __restrict__ bias, const float* __restrict__ resid,
    bf16* __restrict__ outb, float* __restrict__ outf, int M, int N, int K) {
  __shared__ bf16 As[128 * 32];
  __shared__ bf16 Bs[BN * 32];
  const int tid = threadIdx.x;
  const int wid = tid >> 6, lane = tid & 63, g = lane >> 4, q = lane & 15;
  constexpr int FM = (BN == 128) ? 4 : 2;
  constexpr int FN = 4;
  constexpr int WM = (BN == 128) ? 64 : 32;
  const int wr = (BN == 128) ? (wid >> 1) : wid;
  const int wc = (BN == 128) ? (wid & 1) : 0;
  const int row0 = blockIdx.y * 128, col0 = blockIdx.x * BN;
  floatx4 acc[FM][FN] = {};
  const int r0 = tid >> 2;        // staging row (inst 0)
  const int c0 = (tid & 3) * 8;   // staging col
  const bf16* Ab = A + (size_t)row0 * K;
  const bf16* Bb = BT + (size_t)col0 * K;

  for (int k0 = 0; k0 < K; k0 += 32) {
    GLDS16(Ab + (size_t)r0 * K + k0 + c0, (char*)As + wid * 1024);
    GLDS16(Ab + (size_t)(r0 + 64) * K + k0 + c0, (char*)As + 4096 + wid * 1024);
    GLDS16(Bb + (size_t)r0 * K + k0 + c0, (char*)Bs + wid * 1024);
    if constexpr (BN == 128)
      GLDS16(Bb + (size_t)(r0 + 64) * K + k0 + c0, (char*)Bs + 4096 + wid * 1024);
    __syncthreads();
    short8 af[FM], bfr[FN];
#pragma unroll
    for (int m = 0; m < FM; m++)
      af[m] = *(const short8*)&As[(wr * WM + m * 16 + q) * 32 + g * 8];
#pragma unroll
    for (int n = 0; n < FN; n++)
      bfr[n] = *(const short8*)&Bs[(wc * 64 + n * 16 + q) * 32 + g * 8];
#pragma unroll
    for (int m = 0; m < FM; m++)
#pragma unroll
      for (int n = 0; n < FN; n++)
        acc[m][n] =
            __builtin_amdgcn_mfma_f32_16x16x32_bf16(af[m], bfr[n], acc[m][n], 0, 0, 0);
    __syncthreads();
  }

#pragma unroll
  for (int n = 0; n < FN; n++) {
    const int col = col0 + wc * 64 + n * 16 + q;
    const float bv = bias[col];
#pragma unroll
    for (int m = 0; m < FM; m++) {
      const int rowb = row0 + wr * WM + m * 16 + g * 4;
#pragma unroll
      for (int r = 0; r < 4; r++) {
        const size_t idx = (size_t)(rowb + r) * N + col;
        const float v = acc[m][n][r] + bv;
        if (EPI == 0) {
          outb[idx] = f2bf(v);
        } else if (EPI == 1) {
          outf[idx] = v + resid[idx];
        } else {
          const float t = tanhf(0.7978845608028654f * (v + 0.044715f * v * v * v));
          outb[idx] = f2bf(0.5f * v * (1.0f + t));
        }
      }
    }
  }
}

// ---------------- causal flash attention v9: LDS-staged K/V, double-buffered.
// R10 lesson: per-wave scattered L2 loads (885MB, 70x redundancy) are the
// wall; no intra-wave scheduling fixed it. Now: 256-thread block owns one
// (b,h,qblk); all 4 q-waves walk ALL kv tiles (no split, no merge); each tile
// K(8KB)+V(8KB) staged ONCE per block via global_load_lds with XOR-preswizzled
// source (m173), double-buffered (stage t+1 before computing t, one
// vmcnt(0)+barrier per tile). Fragment values bit-identical to v8's.
__global__ __launch_bounds__(256, 2) void kattn(const bf16* __restrict__ qkv,
                                                const bf16* __restrict__ VT,
                                                bf16* __restrict__ y) {
  const int T = 2048, C3 = 2304;
  const int tid = threadIdx.x;
  const int w = tid >> 6, lane = tid & 63;
  const int g = lane >> 4, qi = lane & 15;

  // XCD-chunked swizzle: 768 blocks = 8 XCDs x 96; heavy qblk first
  const int bid = blockIdx.x;
  const int lb = (bid & 7) * 96 + (bid >> 3);
  const int qblk = 31 - (lb & 31);
  const int h = (lb >> 5) % 12, b = (lb >> 5) / 12;
  const int q0w = qblk * 64 + w * 16;
  const int qrow = q0w + qi;               // this lane's q row

  const bf16* Qb = qkv + (size_t)b * T * C3 + h * 64;
  const char* Ksrc = (const char*)(Qb + 768);                      // row stride 4608
  const char* Vsrc = (const char*)(VT + (size_t)(b * 12 + h) * 64 * T);  // d stride 4096

  // double-buffered tiles: [buf][ K 8KB | V 8KB ]
  __shared__ __align__(16) char smem[32768];

  const int nt = qblk + 1;  // KV tiles of 64

  // Q as B-fragment: col=q=qi, rows d = s*32 + g*8 .. +7
  short8 qf[2];
#pragma unroll
  for (int s = 0; s < 2; s++)
    qf[s] = *(const short8*)(Qb + (size_t)qrow * C3 + s * 32 + g * 8);

  const int kvb = (qi >> 2) * 8 + (qi & 3);
  // staging swizzle: lane l stages LDS row r=c*8+(l>>3), slot l&7; source col
  // slot = (l&7) ^ (r&7)  (involution; reader applies same XOR)
  const unsigned swz = (unsigned)(((lane & 7) ^ (lane >> 3)) << 4);
  const int srow = lane >> 3;

  float m_run = -1e30f, l_run = 0.f;
  floatx4 o[4] = {};

#define STAGE(t)                                                                   \
  {                                                                                \
    char* base_ = smem + ((t) & 1) * 16384;                                        \
    const int kv0_ = (t) * 64;                                                     \
    _Pragma("unroll")                                                              \
    for (int j = 0; j < 2; j++) {                                                  \
      const int c_ = w * 2 + j;                                                    \
      GLDS16(Ksrc + (size_t)(kv0_ + c_ * 8 + srow) * 4608 + swz, base_ + c_ * 1024); \
      GLDS16(Vsrc + (size_t)(c_ * 8 + srow) * 4096 + kv0_ * 2 + swz,               \
             base_ + 8192 + c_ * 1024);                                            \
    }                                                                              \
  }

  STAGE(0);
  asm volatile("s_waitcnt vmcnt(0)");
  __syncthreads();

  for (int t = 0; t < nt; t++) {
    if (t + 1 < nt) STAGE(t + 1);
    const char* Kl = smem + (t & 1) * 16384;
    const char* Vl = Kl + 8192;
    const int kv0 = t * 64;

    // K fragments from LDS (swizzled): row R, slot s*4+g
    short8 kf[8];
#pragma unroll
    for (int c = 0; c < 4; c++) {
      const int R = kvb + (c & 1) * 4 + (c >> 1) * 32;
#pragma unroll
      for (int s = 0; s < 2; s++)
        kf[c * 2 + s] =
            *(const short8*)(Kl + R * 128 + (((s * 4 + g) ^ (R & 7)) << 4));
    }
    // V fragments from LDS (swizzled): row R2=n*16+qi, slot ks*4+g
    short8 vfr[8];
#pragma unroll
    for (int ks = 0; ks < 2; ks++)
#pragma unroll
      for (int n = 0; n < 4; n++) {
        const int R2 = n * 16 + qi;
        vfr[ks * 4 + n] =
            *(const short8*)(Vl + R2 * 128 + (((ks * 4 + g) ^ (R2 & 7)) << 4));
      }

    // S^T = K Q^T : sacc[c] col=q, row(g*4+r) -> kv = g*8+(c&1)*4+r+(c>>1)*32
    floatx4 sacc[4] = {};
#pragma unroll
    for (int c = 0; c < 4; c++)
#pragma unroll
      for (int s = 0; s < 2; s++)
        sacc[c] =
            __builtin_amdgcn_mfma_f32_16x16x32_bf16(kf[c * 2 + s], qf[s], sacc[c], 0, 0, 0);

    if (kv0 + 63 > q0w) {  // diagonal-ish tile: causal mask
#pragma unroll
      for (int c = 0; c < 4; c++)
#pragma unroll
        for (int r = 0; r < 4; r++) {
          const int kv = kv0 + g * 8 + (c & 1) * 4 + r + (c >> 1) * 32;
          if (kv > qrow) sacc[c][r] = -1e30f;
        }
    }
    float mx = sacc[0][0];
#pragma unroll
    for (int c = 0; c < 4; c++)
#pragma unroll
      for (int r = 0; r < 4; r++) mx = fmaxf(mx, sacc[c][r]);
    mx = fmaxf(mx, __shfl_xor(mx, 16));
    mx = fmaxf(mx, __shfl_xor(mx, 32));
    mx *= 0.125f;
    const float mn = fmaxf(m_run, mx);
    const float al = __expf(m_run - mn);
    float ps = 0.f;
    unsigned pk[8];
#pragma unroll
    for (int c = 0; c < 4; c++) {
      float p0 = __expf(fmaf(sacc[c][0], 0.125f, -mn));
      float p1 = __expf(fmaf(sacc[c][1], 0.125f, -mn));
      float p2 = __expf(fmaf(sacc[c][2], 0.125f, -mn));
      float p3 = __expf(fmaf(sacc[c][3], 0.125f, -mn));
      ps += (p0 + p1) + (p2 + p3);
      pk[c * 2] = cvtpk(p0, p1);
      pk[c * 2 + 1] = cvtpk(p2, p3);
    }
    ps += __shfl_xor(ps, 16);
    ps += __shfl_xor(ps, 32);
    l_run = l_run * al + ps;
    m_run = mn;
#pragma unroll
    for (int n = 0; n < 4; n++) o[n] *= al;

    // O^T += V^T P^T
#pragma unroll
    for (int ks = 0; ks < 2; ks++) {
      uintx4 pu;
      pu.x = pk[ks * 4 + 0];
      pu.y = pk[ks * 4 + 1];
      pu.z = pk[ks * 4 + 2];
      pu.w = pk[ks * 4 + 3];
      const short8 pf = __builtin_bit_cast(short8, pu);
#pragma unroll
      for (int n = 0; n < 4; n++)
        o[n] = __builtin_amdgcn_mfma_f32_16x16x32_bf16(vfr[ks * 4 + n], pf, o[n], 0, 0, 0);
    }

    asm volatile("s_waitcnt vmcnt(0)");  // drain stage(t+1)
    __syncthreads();
  }
#undef STAGE

  // write y directly (no merge): o[n][r] = O^T[d=n*16+g*4+r][q=qi]
  const float inv = 1.0f / l_run;
  bf16* yr = y + (size_t)(b * T + qrow) * 768 + h * 64;
#pragma unroll
  for (int n = 0; n < 4; n++) {
    uint2 pr;
    pr.x = cvtpk(o[n][0] * inv, o[n][1] * inv);
    pr.y = cvtpk(o[n][2] * inv, o[n][3] * inv);
    *(uint2*)(yr + n * 16 + g * 4) = pr;
  }
}

// ---------------- host side
extern "C" void kernel_launch(void* const* d_in, const int* in_sizes, int n_in,
                              void* d_out, int out_size, void* d_ws, size_t ws_size,
                              hipStream_t stream) {
  const float* x      = (const float*)d_in[0];
  const float* ln1_g  = (const float*)d_in[1];
  const float* ln1_b  = (const float*)d_in[2];
  const float* w_attn = (const float*)d_in[3];
  const float* b_attn = (const float*)d_in[4];
  const float* w_proj = (const float*)d_in[5];
  const float* b_proj = (const float*)d_in[6];
  const float* ln2_g  = (const float*)d_in[7];
  const float* ln2_b  = (const float*)d_in[8];
  const float* w_fc   = (const float*)d_in[9];
  const float* b_fc   = (const float*)d_in[10];
  const float* w_fc2  = (const float*)d_in[11];
  const float* b_fc2  = (const float*)d_in[12];
  float* out = (float*)d_out;

  const int M = 4096;  // B*T
  char* p = (char*)d_ws;
  bf16* wT_attn = (bf16*)p; p += (size_t)2304 * 768 * 2;
  bf16* wT_proj = (bf16*)p; p += (size_t)768 * 768 * 2;
  bf16* wT_fc   = (bf16*)p; p += (size_t)3072 * 768 * 2;
  bf16* wT_fc2  = (bf16*)p; p += (size_t)768 * 3072 * 2;
  bf16* h       = (bf16*)p; p += (size_t)M * 768 * 2;
  bf16* qkv     = (bf16*)p;
  bf16* yb      = (bf16*)(p + (size_t)M * 2304 * 2);
  bf16* act     = qkv;      p += (size_t)M * 2304 * 2 + (size_t)M * 768 * 2;
  float* x1     = (float*)p;
  bf16* VT      = (bf16*)p;  // aliases x1: VT dead before x1 is written

  // weights -> bf16 transposed
  kconvT<<<dim3(2304 / 32, 768 / 32), 256, 0, stream>>>(w_attn, wT_attn, 768, 2304);
  kconvT<<<dim3(768 / 32, 768 / 32), 256, 0, stream>>>(w_proj, wT_proj, 768, 768);
  kconvT<<<dim3(3072 / 32, 768 / 32), 256, 0, stream>>>(w_fc, wT_fc, 768, 3072);
  kconvT<<<dim3(768 / 32, 3072 / 32), 256, 0, stream>>>(w_fc2, wT_fc2, 3072, 768);

  // attention branch
  kln<<<M, 256, 0, stream>>>(x, ln1_g, ln1_b, h);
  kgemm<128, 0><<<dim3(2304 / 128, M / 128), 256, 0, stream>>>(
      h, wT_attn, b_attn, nullptr, qkv, nullptr, M, 2304, 768);
  kxpose<<<dim3(32, 12, 2), 256, 0, stream>>>(qkv, VT);
  kattn<<<dim3(768), 256, 0, stream>>>(qkv, VT, yb);
  kgemm<64, 1><<<dim3(768 / 64, M / 128), 256, 0, stream>>>(
      yb, wT_proj, b_proj, x, nullptr, x1, M, 768, 768);

  // MLP branch
  kln<<<M, 256, 0, stream>>>(x1, ln2_g, ln2_b, h);
  kgemm<128, 2><<<dim3(3072 / 128, M / 128), 256, 0, stream>>>(
      h, wT_fc, b_fc, nullptr, act, nullptr, M, 3072, 768);
  kgemm<64, 1><<<dim3(768 / 64, M / 128), 256, 0, stream>>>(
      act, wT_fc2, b_fc2, x1, nullptr, out, M, 768, 3072);
}

// Round 12
// 212.937 us; speedup vs baseline: 1.5390x; 1.0551x over previous
//
#include <hip/hip_runtime.h>
#include <hip/hip_bf16.h>
#include <math.h>

typedef __hip_bfloat16 bf16;
typedef __attribute__((ext_vector_type(8))) short short8;
typedef __attribute__((ext_vector_type(4))) float floatx4;
typedef __attribute__((ext_vector_type(4))) unsigned uintx4;

#define GLDS16(g, l) __builtin_amdgcn_global_load_lds( \
    (const __attribute__((address_space(1))) void*)(g), \
    (__attribute__((address_space(3))) void*)(l), 16, 0, 0)

__device__ __forceinline__ bf16 f2bf(float v) { return __float2bfloat16(v); }

// pack two f32 -> one u32 of two bf16 (lo = a, hi = b)
__device__ __forceinline__ unsigned cvtpk(float a, float b) {
  unsigned r;
  asm volatile("v_cvt_pk_bf16_f32 %0, %1, %2" : "=v"(r) : "v"(a), "v"(b));
  return r;
}

// ---------------- weight convert + transpose: w[K][N] f32 -> wT[N][K] bf16
__global__ __launch_bounds__(256) void kconvT(const float* __restrict__ w,
                                              bf16* __restrict__ wT,
                                              int K, int N) {
  __shared__ float tile[32][33];
  const int n0 = blockIdx.x * 32, k0 = blockIdx.y * 32;
  const int tc = threadIdx.x & 31, tr = threadIdx.x >> 5;  // tr 0..7
#pragma unroll
  for (int p = 0; p < 4; p++)
    tile[tr + p * 8][tc] = w[(size_t)(k0 + tr + p * 8) * N + n0 + tc];
  __syncthreads();
#pragma unroll
  for (int p = 0; p < 4; p++)
    wT[(size_t)(n0 + tr + p * 8) * K + k0 + tc] = f2bf(tile[tc][tr + p * 8]);
}

// ---------------- LayerNorm: f32 [rows][768] -> bf16
__global__ __launch_bounds__(256) void kln(const float* __restrict__ x,
                                           const float* __restrict__ gw,
                                           const float* __restrict__ bw,
                                           bf16* __restrict__ out) {
  const int row = blockIdx.x, tid = threadIdx.x;
  const float* xr = x + (size_t)row * 768;
  float v0 = xr[tid], v1 = xr[tid + 256], v2 = xr[tid + 512];
  float s = v0 + v1 + v2;
  float s2 = v0 * v0 + v1 * v1 + v2 * v2;
#pragma unroll
  for (int off = 1; off < 64; off <<= 1) {
    s += __shfl_xor(s, off);
    s2 += __shfl_xor(s2, off);
  }
  __shared__ float red[8];
  const int wid = tid >> 6, lane = tid & 63;
  if (lane == 0) { red[wid] = s; red[4 + wid] = s2; }
  __syncthreads();
  s = red[0] + red[1] + red[2] + red[3];
  s2 = red[4] + red[5] + red[6] + red[7];
  const float mu = s * (1.f / 768.f);
  const float rst = rsqrtf(fmaxf(s2 * (1.f / 768.f) - mu * mu, 0.f) + 1e-5f);
  bf16* orow = out + (size_t)row * 768;
  orow[tid] = f2bf((v0 - mu) * rst * gw[tid] + bw[tid]);
  orow[tid + 256] = f2bf((v1 - mu) * rst * gw[tid + 256] + bw[tid + 256]);
  orow[tid + 512] = f2bf((v2 - mu) * rst * gw[tid + 512] + bw[tid + 512]);
}

// ---------------- V transpose: qkv[b*T+t][1536 + h*64 + d] -> VT[b][h][d][t]
__global__ __launch_bounds__(256) void kxpose(const bf16* __restrict__ qkv,
                                              bf16* __restrict__ VT) {
  const int T = 2048, C3 = 2304;
  const int t0 = blockIdx.x * 64, h = blockIdx.y, b = blockIdx.z;
  const int tid = threadIdx.x;
  __shared__ short tile[64][66];
  const bf16* src = qkv + (size_t)b * T * C3 + 1536 + h * 64;
  const int tr = tid >> 3, c = tid & 7;
#pragma unroll
  for (int p = 0; p < 2; p++) {
    short8 v = *(const short8*)(src + (size_t)(t0 + tr + p * 32) * C3 + c * 8);
    *(short8*)&tile[tr + p * 32][c * 8] = v;
  }
  __syncthreads();
  bf16* dst = VT + ((size_t)(b * 12 + h) * 64) * T + t0;
#pragma unroll
  for (int p = 0; p < 2; p++) {
    const int d = (tid >> 3) + p * 32, tc = tid & 7;
    short8 v;
#pragma unroll
    for (int j = 0; j < 8; j++) v[j] = tile[tc * 8 + j][d];
    *(short8*)(dst + (size_t)d * T + tc * 8) = v;
  }
}

// ---------------- GEMM v2: 2-phase double-buffered LDS + XOR bank swizzle.
// R11: old loop staged tile t then barriered on it immediately (full latency
// exposed; grid-limited to ~1.5 blocks/CU for BN=64 -> nothing hid it), and
// [*][32]bf16 rows (64B) were an 8-way conflict on ds_read_b128 (3.5M counts).
// Now: STAGE(t+1) issued BEFORE ds_read+MFMA of t (latency hides under
// compute); LDS slot swizzled by (row>>1)&3 (pre-swizzled global source,
// reader slot g^((q>>1)&3)) -> ~2-way, free.
// EPI 0: +bias -> bf16   EPI 1: +bias+resid -> f32   EPI 2: +bias, GELU -> bf16
template <int BN, int EPI>
__global__ __launch_bounds__(256, 2) void kgemm(
    const bf16* __restrict__ A, const bf16* __restrict__ BT,
    const float* __restrict__ bias, const float* __restrict__ resid,
    bf16* __restrict__ outb, float* __restrict__ outf, int M, int N, int K) {
  __shared__ bf16 As[2][128 * 32];
  __shared__ bf16 Bs[2][BN * 32];
  const int tid = threadIdx.x;
  const int wid = tid >> 6, lane = tid & 63, g = lane >> 4, q = lane & 15;
  constexpr int FM = (BN == 128) ? 4 : 2;
  constexpr int FN = 4;
  constexpr int WM = (BN == 128) ? 64 : 32;
  const int wr = (BN == 128) ? (wid >> 1) : wid;
  const int wc = (BN == 128) ? (wid & 1) : 0;
  const int row0 = blockIdx.y * 128, col0 = blockIdx.x * BN;
  floatx4 acc[FM][FN] = {};
  const int r0 = tid >> 2;                               // staging row
  const int c0 = (((tid & 3) ^ ((r0 >> 1) & 3))) * 8;    // pre-swizzled src col
  const int lsl = (g ^ ((q >> 1) & 3)) * 16;             // reader slot (bytes)
  const bf16* Ab = A + (size_t)row0 * K;
  const bf16* Bb = BT + (size_t)col0 * K;

  auto STAGE = [&](int kk, int buf) {
    GLDS16(Ab + (size_t)r0 * K + kk + c0, (char*)&As[buf][0] + wid * 1024);
    GLDS16(Ab + (size_t)(r0 + 64) * K + kk + c0,
           (char*)&As[buf][0] + 4096 + wid * 1024);
    GLDS16(Bb + (size_t)r0 * K + kk + c0, (char*)&Bs[buf][0] + wid * 1024);
    if constexpr (BN == 128)
      GLDS16(Bb + (size_t)(r0 + 64) * K + kk + c0,
             (char*)&Bs[buf][0] + 4096 + wid * 1024);
  };

  const int nk = K >> 5;
  STAGE(0, 0);
  asm volatile("s_waitcnt vmcnt(0)");
  __syncthreads();

  for (int kt = 0; kt < nk; kt++) {
    if (kt + 1 < nk) STAGE((kt + 1) << 5, (kt + 1) & 1);
    const char* Ac = (const char*)&As[kt & 1][0];
    const char* Bc = (const char*)&Bs[kt & 1][0];
    short8 af[FM], bfr[FN];
#pragma unroll
    for (int m = 0; m < FM; m++)
      af[m] = *(const short8*)(Ac + (wr * WM + m * 16 + q) * 64 + lsl);
#pragma unroll
    for (int n = 0; n < FN; n++)
      bfr[n] = *(const short8*)(Bc + (wc * 64 + n * 16 + q) * 64 + lsl);
#pragma unroll
    for (int m = 0; m < FM; m++)
#pragma unroll
      for (int n = 0; n < FN; n++)
        acc[m][n] =
            __builtin_amdgcn_mfma_f32_16x16x32_bf16(af[m], bfr[n], acc[m][n], 0, 0, 0);
    asm volatile("s_waitcnt vmcnt(0)");
    __syncthreads();
  }

#pragma unroll
  for (int n = 0; n < FN; n++) {
    const int col = col0 + wc * 64 + n * 16 + q;
    const float bv = bias[col];
#pragma unroll
    for (int m = 0; m < FM; m++) {
      const int rowb = row0 + wr * WM + m * 16 + g * 4;
#pragma unroll
      for (int r = 0; r < 4; r++) {
        const size_t idx = (size_t)(rowb + r) * N + col;
        const float v = acc[m][n][r] + bv;
        if (EPI == 0) {
          outb[idx] = f2bf(v);
        } else if (EPI == 1) {
          outf[idx] = v + resid[idx];
        } else {
          const float t = tanhf(0.7978845608028654f * (v + 0.044715f * v * v * v));
          outb[idx] = f2bf(0.5f * v * (1.0f + t));
        }
      }
    }
  }
}

// ---------------- causal flash attention v9: LDS-staged K/V, double-buffered.
// (unchanged from R11 — verified passing)
__global__ __launch_bounds__(256, 2) void kattn(const bf16* __restrict__ qkv,
                                                const bf16* __restrict__ VT,
                                                bf16* __restrict__ y) {
  const int T = 2048, C3 = 2304;
  const int tid = threadIdx.x;
  const int w = tid >> 6, lane = tid & 63;
  const int g = lane >> 4, qi = lane & 15;

  const int bid = blockIdx.x;
  const int lb = (bid & 7) * 96 + (bid >> 3);
  const int qblk = 31 - (lb & 31);
  const int h = (lb >> 5) % 12, b = (lb >> 5) / 12;
  const int q0w = qblk * 64 + w * 16;
  const int qrow = q0w + qi;

  const bf16* Qb = qkv + (size_t)b * T * C3 + h * 64;
  const char* Ksrc = (const char*)(Qb + 768);
  const char* Vsrc = (const char*)(VT + (size_t)(b * 12 + h) * 64 * T);

  __shared__ __align__(16) char smem[32768];

  const int nt = qblk + 1;

  short8 qf[2];
#pragma unroll
  for (int s = 0; s < 2; s++)
    qf[s] = *(const short8*)(Qb + (size_t)qrow * C3 + s * 32 + g * 8);

  const int kvb = (qi >> 2) * 8 + (qi & 3);
  const unsigned swz = (unsigned)(((lane & 7) ^ (lane >> 3)) << 4);
  const int srow = lane >> 3;

  float m_run = -1e30f, l_run = 0.f;
  floatx4 o[4] = {};

#define STAGE(t)                                                                   \
  {                                                                                \
    char* base_ = smem + ((t) & 1) * 16384;                                        \
    const int kv0_ = (t) * 64;                                                     \
    _Pragma("unroll")                                                              \
    for (int j = 0; j < 2; j++) {                                                  \
      const int c_ = w * 2 + j;                                                    \
      GLDS16(Ksrc + (size_t)(kv0_ + c_ * 8 + srow) * 4608 + swz, base_ + c_ * 1024); \
      GLDS16(Vsrc + (size_t)(c_ * 8 + srow) * 4096 + kv0_ * 2 + swz,               \
             base_ + 8192 + c_ * 1024);                                            \
    }                                                                              \
  }

  STAGE(0);
  asm volatile("s_waitcnt vmcnt(0)");
  __syncthreads();

  for (int t = 0; t < nt; t++) {
    if (t + 1 < nt) STAGE(t + 1);
    const char* Kl = smem + (t & 1) * 16384;
    const char* Vl = Kl + 8192;
    const int kv0 = t * 64;

    short8 kf[8];
#pragma unroll
    for (int c = 0; c < 4; c++) {
      const int R = kvb + (c & 1) * 4 + (c >> 1) * 32;
#pragma unroll
      for (int s = 0; s < 2; s++)
        kf[c * 2 + s] =
            *(const short8*)(Kl + R * 128 + (((s * 4 + g) ^ (R & 7)) << 4));
    }
    short8 vfr[8];
#pragma unroll
    for (int ks = 0; ks < 2; ks++)
#pragma unroll
      for (int n = 0; n < 4; n++) {
        const int R2 = n * 16 + qi;
        vfr[ks * 4 + n] =
            *(const short8*)(Vl + R2 * 128 + (((ks * 4 + g) ^ (R2 & 7)) << 4));
      }

    floatx4 sacc[4] = {};
#pragma unroll
    for (int c = 0; c < 4; c++)
#pragma unroll
      for (int s = 0; s < 2; s++)
        sacc[c] =
            __builtin_amdgcn_mfma_f32_16x16x32_bf16(kf[c * 2 + s], qf[s], sacc[c], 0, 0, 0);

    if (kv0 + 63 > q0w) {
#pragma unroll
      for (int c = 0; c < 4; c++)
#pragma unroll
        for (int r = 0; r < 4; r++) {
          const int kv = kv0 + g * 8 + (c & 1) * 4 + r + (c >> 1) * 32;
          if (kv > qrow) sacc[c][r] = -1e30f;
        }
    }
    float mx = sacc[0][0];
#pragma unroll
    for (int c = 0; c < 4; c++)
#pragma unroll
      for (int r = 0; r < 4; r++) mx = fmaxf(mx, sacc[c][r]);
    mx = fmaxf(mx, __shfl_xor(mx, 16));
    mx = fmaxf(mx, __shfl_xor(mx, 32));
    mx *= 0.125f;
    const float mn = fmaxf(m_run, mx);
    const float al = __expf(m_run - mn);
    float ps = 0.f;
    unsigned pk[8];
#pragma unroll
    for (int c = 0; c < 4; c++) {
      float p0 = __expf(fmaf(sacc[c][0], 0.125f, -mn));
      float p1 = __expf(fmaf(sacc[c][1], 0.125f, -mn));
      float p2 = __expf(fmaf(sacc[c][2], 0.125f, -mn));
      float p3 = __expf(fmaf(sacc[c][3], 0.125f, -mn));
      ps += (p0 + p1) + (p2 + p3);
      pk[c * 2] = cvtpk(p0, p1);
      pk[c * 2 + 1] = cvtpk(p2, p3);
    }
    ps += __shfl_xor(ps, 16);
    ps += __shfl_xor(ps, 32);
    l_run = l_run * al + ps;
    m_run = mn;
#pragma unroll
    for (int n = 0; n < 4; n++) o[n] *= al;

#pragma unroll
    for (int ks = 0; ks < 2; ks++) {
      uintx4 pu;
      pu.x = pk[ks * 4 + 0];
      pu.y = pk[ks * 4 + 1];
      pu.z = pk[ks * 4 + 2];
      pu.w = pk[ks * 4 + 3];
      const short8 pf = __builtin_bit_cast(short8, pu);
#pragma unroll
      for (int n = 0; n < 4; n++)
        o[n] = __builtin_amdgcn_mfma_f32_16x16x32_bf16(vfr[ks * 4 + n], pf, o[n], 0, 0, 0);
    }

    asm volatile("s_waitcnt vmcnt(0)");
    __syncthreads();
  }
#undef STAGE

  const float inv = 1.0f / l_run;
  bf16* yr = y + (size_t)(b * T + qrow) * 768 + h * 64;
#pragma unroll
  for (int n = 0; n < 4; n++) {
    uint2 pr;
    pr.x = cvtpk(o[n][0] * inv, o[n][1] * inv);
    pr.y = cvtpk(o[n][2] * inv, o[n][3] * inv);
    *(uint2*)(yr + n * 16 + g * 4) = pr;
  }
}

// ---------------- host side
extern "C" void kernel_launch(void* const* d_in, const int* in_sizes, int n_in,
                              void* d_out, int out_size, void* d_ws, size_t ws_size,
                              hipStream_t stream) {
  const float* x      = (const float*)d_in[0];
  const float* ln1_g  = (const float*)d_in[1];
  const float* ln1_b  = (const float*)d_in[2];
  const float* w_attn = (const float*)d_in[3];
  const float* b_attn = (const float*)d_in[4];
  const float* w_proj = (const float*)d_in[5];
  const float* b_proj = (const float*)d_in[6];
  const float* ln2_g  = (const float*)d_in[7];
  const float* ln2_b  = (const float*)d_in[8];
  const float* w_fc   = (const float*)d_in[9];
  const float* b_fc   = (const float*)d_in[10];
  const float* w_fc2  = (const float*)d_in[11];
  const float* b_fc2  = (const float*)d_in[12];
  float* out = (float*)d_out;

  const int M = 4096;  // B*T
  char* p = (char*)d_ws;
  bf16* wT_attn = (bf16*)p; p += (size_t)2304 * 768 * 2;
  bf16* wT_proj = (bf16*)p; p += (size_t)768 * 768 * 2;
  bf16* wT_fc   = (bf16*)p; p += (size_t)3072 * 768 * 2;
  bf16* wT_fc2  = (bf16*)p; p += (size_t)768 * 3072 * 2;
  bf16* h       = (bf16*)p; p += (size_t)M * 768 * 2;
  bf16* qkv     = (bf16*)p;
  bf16* yb      = (bf16*)(p + (size_t)M * 2304 * 2);
  bf16* act     = qkv;      p += (size_t)M * 2304 * 2 + (size_t)M * 768 * 2;
  float* x1     = (float*)p;
  bf16* VT      = (bf16*)p;  // aliases x1: VT dead before x1 is written

  // weights -> bf16 transposed
  kconvT<<<dim3(2304 / 32, 768 / 32), 256, 0, stream>>>(w_attn, wT_attn, 768, 2304);
  kconvT<<<dim3(768 / 32, 768 / 32), 256, 0, stream>>>(w_proj, wT_proj, 768, 768);
  kconvT<<<dim3(3072 / 32, 768 / 32), 256, 0, stream>>>(w_fc, wT_fc, 768, 3072);
  kconvT<<<dim3(768 / 32, 3072 / 32), 256, 0, stream>>>(w_fc2, wT_fc2, 3072, 768);

  // attention branch
  kln<<<M, 256, 0, stream>>>(x, ln1_g, ln1_b, h);
  kgemm<128, 0><<<dim3(2304 / 128, M / 128), 256, 0, stream>>>(
      h, wT_attn, b_attn, nullptr, qkv, nullptr, M, 2304, 768);
  kxpose<<<dim3(32, 12, 2), 256, 0, stream>>>(qkv, VT);
  kattn<<<dim3(768), 256, 0, stream>>>(qkv, VT, yb);
  kgemm<64, 1><<<dim3(768 / 64, M / 128), 256, 0, stream>>>(
      yb, wT_proj, b_proj, x, nullptr, x1, M, 768, 768);

  // MLP branch
  kln<<<M, 256, 0, stream>>>(x1, ln2_g, ln2_b, h);
  kgemm<128, 2><<<dim3(3072 / 128, M / 128), 256, 0, stream>>>(
      h, wT_fc, b_fc, nullptr, act, nullptr, M, 3072, 768);
  kgemm<64, 1><<<dim3(768 / 64, M / 128), 256, 0, stream>>>(
      act, wT_fc2, b_fc2, x1, nullptr, out, M, 768, 3072);
}

// Round 13
// 211.101 us; speedup vs baseline: 1.5523x; 1.0087x over previous
//
#include <hip/hip_runtime.h>
#include <hip/hip_bf16.h>
#include <math.h>

typedef __hip_bfloat16 bf16;
typedef __attribute__((ext_vector_type(8))) short short8;
typedef __attribute__((ext_vector_type(4))) float floatx4;
typedef __attribute__((ext_vector_type(4))) unsigned uintx4;

#define GLDS16(g, l) __builtin_amdgcn_global_load_lds( \
    (const __attribute__((address_space(1))) void*)(g), \
    (__attribute__((address_space(3))) void*)(l), 16, 0, 0)

__device__ __forceinline__ bf16 f2bf(float v) { return __float2bfloat16(v); }

// pack two f32 -> one u32 of two bf16 (lo = a, hi = b)
__device__ __forceinline__ unsigned cvtpk(float a, float b) {
  unsigned r;
  asm volatile("v_cvt_pk_bf16_f32 %0, %1, %2" : "=v"(r) : "v"(a), "v"(b));
  return r;
}

// ---------------- weight convert + transpose: w[K][N] f32 -> wT[N][K] bf16
__global__ __launch_bounds__(256) void kconvT(const float* __restrict__ w,
                                              bf16* __restrict__ wT,
                                              int K, int N) {
  __shared__ float tile[32][33];
  const int n0 = blockIdx.x * 32, k0 = blockIdx.y * 32;
  const int tc = threadIdx.x & 31, tr = threadIdx.x >> 5;  // tr 0..7
#pragma unroll
  for (int p = 0; p < 4; p++)
    tile[tr + p * 8][tc] = w[(size_t)(k0 + tr + p * 8) * N + n0 + tc];
  __syncthreads();
#pragma unroll
  for (int p = 0; p < 4; p++)
    wT[(size_t)(n0 + tr + p * 8) * K + k0 + tc] = f2bf(tile[tc][tr + p * 8]);
}

// ---------------- LayerNorm: f32 [rows][768] -> bf16
__global__ __launch_bounds__(256) void kln(const float* __restrict__ x,
                                           const float* __restrict__ gw,
                                           const float* __restrict__ bw,
                                           bf16* __restrict__ out) {
  const int row = blockIdx.x, tid = threadIdx.x;
  const float* xr = x + (size_t)row * 768;
  float v0 = xr[tid], v1 = xr[tid + 256], v2 = xr[tid + 512];
  float s = v0 + v1 + v2;
  float s2 = v0 * v0 + v1 * v1 + v2 * v2;
#pragma unroll
  for (int off = 1; off < 64; off <<= 1) {
    s += __shfl_xor(s, off);
    s2 += __shfl_xor(s2, off);
  }
  __shared__ float red[8];
  const int wid = tid >> 6, lane = tid & 63;
  if (lane == 0) { red[wid] = s; red[4 + wid] = s2; }
  __syncthreads();
  s = red[0] + red[1] + red[2] + red[3];
  s2 = red[4] + red[5] + red[6] + red[7];
  const float mu = s * (1.f / 768.f);
  const float rst = rsqrtf(fmaxf(s2 * (1.f / 768.f) - mu * mu, 0.f) + 1e-5f);
  bf16* orow = out + (size_t)row * 768;
  orow[tid] = f2bf((v0 - mu) * rst * gw[tid] + bw[tid]);
  orow[tid + 256] = f2bf((v1 - mu) * rst * gw[tid + 256] + bw[tid + 256]);
  orow[tid + 512] = f2bf((v2 - mu) * rst * gw[tid + 512] + bw[tid + 512]);
}

// ---------------- V transpose: qkv[b*T+t][1536 + h*64 + d] -> VT[b][h][d][t]
__global__ __launch_bounds__(256) void kxpose(const bf16* __restrict__ qkv,
                                              bf16* __restrict__ VT) {
  const int T = 2048, C3 = 2304;
  const int t0 = blockIdx.x * 64, h = blockIdx.y, b = blockIdx.z;
  const int tid = threadIdx.x;
  __shared__ short tile[64][66];
  const bf16* src = qkv + (size_t)b * T * C3 + 1536 + h * 64;
  const int tr = tid >> 3, c = tid & 7;
#pragma unroll
  for (int p = 0; p < 2; p++) {
    short8 v = *(const short8*)(src + (size_t)(t0 + tr + p * 32) * C3 + c * 8);
    *(short8*)&tile[tr + p * 32][c * 8] = v;
  }
  __syncthreads();
  bf16* dst = VT + ((size_t)(b * 12 + h) * 64) * T + t0;
#pragma unroll
  for (int p = 0; p < 2; p++) {
    const int d = (tid >> 3) + p * 32, tc = tid & 7;
    short8 v;
#pragma unroll
    for (int j = 0; j < 8; j++) v[j] = tile[tc * 8 + j][d];
    *(short8*)(dst + (size_t)d * T + tc * 8) = v;
  }
}

// ---------------- GEMM v3: depth-3 LDS pipeline, counted vmcnt, XCD swizzle.
// R12: 2-phase dbuf+swizzle zeroed bank conflicts (3.5M->0) but BN=64 grids
// are 1.5 blocks/CU (grid-limited; 14% occ) and 1-deep prefetch (~300cy) <
// HBM latency (~900cy) -> stall per K-step; A-panels re-fetched ~4x across
// XCD L2s (FETCH 109MB). Now: 3 buffers, stage t+2 each iter, counted
// vmcnt(2L) so 2 stages stay in flight across barriers (T3+T4); 1D grid with
// bijective XCD-chunked swizzle so blocks sharing an A-panel share an L2.
// EPI 0: +bias -> bf16   EPI 1: +bias+resid -> f32   EPI 2: +bias, GELU -> bf16
template <int BN, int EPI>
__global__ __launch_bounds__(256, 2) void kgemm(
    const bf16* __restrict__ A, const bf16* __restrict__ BT,
    const float* __restrict__ bias, const float* __restrict__ resid,
    bf16* __restrict__ outb, float* __restrict__ outf, int M, int N, int K,
    int NXB) {
  __shared__ bf16 As[3][128 * 32];
  __shared__ bf16 Bs[3][BN * 32];
  const int tid = threadIdx.x;
  const int wid = tid >> 6, lane = tid & 63, g = lane >> 4, q = lane & 15;
  constexpr int FM = (BN == 128) ? 4 : 2;
  constexpr int FN = 4;
  constexpr int WM = (BN == 128) ? 64 : 32;
  const int wr = (BN == 128) ? (wid >> 1) : wid;
  const int wc = (BN == 128) ? (wid & 1) : 0;

  // bijective XCD-chunked swizzle (gridDim.x divisible by 8): consecutive
  // logical blocks (same A row-panel) land on the same XCD's L2.
  const int bid = blockIdx.x;
  const int lb = (bid & 7) * ((int)gridDim.x >> 3) + (bid >> 3);
  const int row0 = (lb / NXB) * 128, col0 = (lb % NXB) * BN;

  floatx4 acc[FM][FN] = {};
  const int r0 = tid >> 2;                               // staging row
  const int c0 = (((tid & 3) ^ ((r0 >> 1) & 3))) * 8;    // pre-swizzled src col
  const int lsl = (g ^ ((q >> 1) & 3)) * 16;             // reader slot (bytes)
  const bf16* Ab = A + (size_t)row0 * K;
  const bf16* Bb = BT + (size_t)col0 * K;

  auto STAGE = [&](int kk, int buf) {
    GLDS16(Ab + (size_t)r0 * K + kk + c0, (char*)&As[buf][0] + wid * 1024);
    GLDS16(Ab + (size_t)(r0 + 64) * K + kk + c0,
           (char*)&As[buf][0] + 4096 + wid * 1024);
    GLDS16(Bb + (size_t)r0 * K + kk + c0, (char*)&Bs[buf][0] + wid * 1024);
    if constexpr (BN == 128)
      GLDS16(Bb + (size_t)(r0 + 64) * K + kk + c0,
             (char*)&Bs[buf][0] + 4096 + wid * 1024);
  };

  const int nk = K >> 5;
  STAGE(0, 0);
  STAGE(32, 1);

  for (int kt = 0; kt < nk; kt++) {
    // stage t+2 (its buffer was last read at iter t-1; safe after end barrier)
    if (kt + 2 < nk) {
      STAGE((kt + 2) << 5, (kt + 2) % 3);
      if constexpr (BN == 128) asm volatile("s_waitcnt vmcnt(8)");
      else asm volatile("s_waitcnt vmcnt(6)");
    } else if (kt + 1 < nk) {
      if constexpr (BN == 128) asm volatile("s_waitcnt vmcnt(4)");
      else asm volatile("s_waitcnt vmcnt(3)");
    } else {
      asm volatile("s_waitcnt vmcnt(0)");
    }
    __syncthreads();  // buffer kt valid for all waves

    const char* Ac = (const char*)&As[kt % 3][0];
    const char* Bc = (const char*)&Bs[kt % 3][0];
    short8 af[FM], bfr[FN];
#pragma unroll
    for (int m = 0; m < FM; m++)
      af[m] = *(const short8*)(Ac + (wr * WM + m * 16 + q) * 64 + lsl);
#pragma unroll
    for (int n = 0; n < FN; n++)
      bfr[n] = *(const short8*)(Bc + (wc * 64 + n * 16 + q) * 64 + lsl);
#pragma unroll
    for (int m = 0; m < FM; m++)
#pragma unroll
      for (int n = 0; n < FN; n++)
        acc[m][n] =
            __builtin_amdgcn_mfma_f32_16x16x32_bf16(af[m], bfr[n], acc[m][n], 0, 0, 0);
    __syncthreads();  // all waves done reading buffer kt (overwritten at kt+1)
  }

#pragma unroll
  for (int n = 0; n < FN; n++) {
    const int col = col0 + wc * 64 + n * 16 + q;
    const float bv = bias[col];
#pragma unroll
    for (int m = 0; m < FM; m++) {
      const int rowb = row0 + wr * WM + m * 16 + g * 4;
#pragma unroll
      for (int r = 0; r < 4; r++) {
        const size_t idx = (size_t)(rowb + r) * N + col;
        const float v = acc[m][n][r] + bv;
        if (EPI == 0) {
          outb[idx] = f2bf(v);
        } else if (EPI == 1) {
          outf[idx] = v + resid[idx];
        } else {
          const float t = tanhf(0.7978845608028654f * (v + 0.044715f * v * v * v));
          outb[idx] = f2bf(0.5f * v * (1.0f + t));
        }
      }
    }
  }
}

// ---------------- causal flash attention v9: LDS-staged K/V, double-buffered.
// (unchanged from R11 — verified passing)
__global__ __launch_bounds__(256, 2) void kattn(const bf16* __restrict__ qkv,
                                                const bf16* __restrict__ VT,
                                                bf16* __restrict__ y) {
  const int T = 2048, C3 = 2304;
  const int tid = threadIdx.x;
  const int w = tid >> 6, lane = tid & 63;
  const int g = lane >> 4, qi = lane & 15;

  const int bid = blockIdx.x;
  const int lb = (bid & 7) * 96 + (bid >> 3);
  const int qblk = 31 - (lb & 31);
  const int h = (lb >> 5) % 12, b = (lb >> 5) / 12;
  const int q0w = qblk * 64 + w * 16;
  const int qrow = q0w + qi;

  const bf16* Qb = qkv + (size_t)b * T * C3 + h * 64;
  const char* Ksrc = (const char*)(Qb + 768);
  const char* Vsrc = (const char*)(VT + (size_t)(b * 12 + h) * 64 * T);

  __shared__ __align__(16) char smem[32768];

  const int nt = qblk + 1;

  short8 qf[2];
#pragma unroll
  for (int s = 0; s < 2; s++)
    qf[s] = *(const short8*)(Qb + (size_t)qrow * C3 + s * 32 + g * 8);

  const int kvb = (qi >> 2) * 8 + (qi & 3);
  const unsigned swz = (unsigned)(((lane & 7) ^ (lane >> 3)) << 4);
  const int srow = lane >> 3;

  float m_run = -1e30f, l_run = 0.f;
  floatx4 o[4] = {};

#define STAGE(t)                                                                   \
  {                                                                                \
    char* base_ = smem + ((t) & 1) * 16384;                                        \
    const int kv0_ = (t) * 64;                                                     \
    _Pragma("unroll")                                                              \
    for (int j = 0; j < 2; j++) {                                                  \
      const int c_ = w * 2 + j;                                                    \
      GLDS16(Ksrc + (size_t)(kv0_ + c_ * 8 + srow) * 4608 + swz, base_ + c_ * 1024); \
      GLDS16(Vsrc + (size_t)(c_ * 8 + srow) * 4096 + kv0_ * 2 + swz,               \
             base_ + 8192 + c_ * 1024);                                            \
    }                                                                              \
  }

  STAGE(0);
  asm volatile("s_waitcnt vmcnt(0)");
  __syncthreads();

  for (int t = 0; t < nt; t++) {
    if (t + 1 < nt) STAGE(t + 1);
    const char* Kl = smem + (t & 1) * 16384;
    const char* Vl = Kl + 8192;
    const int kv0 = t * 64;

    short8 kf[8];
#pragma unroll
    for (int c = 0; c < 4; c++) {
      const int R = kvb + (c & 1) * 4 + (c >> 1) * 32;
#pragma unroll
      for (int s = 0; s < 2; s++)
        kf[c * 2 + s] =
            *(const short8*)(Kl + R * 128 + (((s * 4 + g) ^ (R & 7)) << 4));
    }
    short8 vfr[8];
#pragma unroll
    for (int ks = 0; ks < 2; ks++)
#pragma unroll
      for (int n = 0; n < 4; n++) {
        const int R2 = n * 16 + qi;
        vfr[ks * 4 + n] =
            *(const short8*)(Vl + R2 * 128 + (((ks * 4 + g) ^ (R2 & 7)) << 4));
      }

    floatx4 sacc[4] = {};
#pragma unroll
    for (int c = 0; c < 4; c++)
#pragma unroll
      for (int s = 0; s < 2; s++)
        sacc[c] =
            __builtin_amdgcn_mfma_f32_16x16x32_bf16(kf[c * 2 + s], qf[s], sacc[c], 0, 0, 0);

    if (kv0 + 63 > q0w) {
#pragma unroll
      for (int c = 0; c < 4; c++)
#pragma unroll
        for (int r = 0; r < 4; r++) {
          const int kv = kv0 + g * 8 + (c & 1) * 4 + r + (c >> 1) * 32;
          if (kv > qrow) sacc[c][r] = -1e30f;
        }
    }
    float mx = sacc[0][0];
#pragma unroll
    for (int c = 0; c < 4; c++)
#pragma unroll
      for (int r = 0; r < 4; r++) mx = fmaxf(mx, sacc[c][r]);
    mx = fmaxf(mx, __shfl_xor(mx, 16));
    mx = fmaxf(mx, __shfl_xor(mx, 32));
    mx *= 0.125f;
    const float mn = fmaxf(m_run, mx);
    const float al = __expf(m_run - mn);
    float ps = 0.f;
    unsigned pk[8];
#pragma unroll
    for (int c = 0; c < 4; c++) {
      float p0 = __expf(fmaf(sacc[c][0], 0.125f, -mn));
      float p1 = __expf(fmaf(sacc[c][1], 0.125f, -mn));
      float p2 = __expf(fmaf(sacc[c][2], 0.125f, -mn));
      float p3 = __expf(fmaf(sacc[c][3], 0.125f, -mn));
      ps += (p0 + p1) + (p2 + p3);
      pk[c * 2] = cvtpk(p0, p1);
      pk[c * 2 + 1] = cvtpk(p2, p3);
    }
    ps += __shfl_xor(ps, 16);
    ps += __shfl_xor(ps, 32);
    l_run = l_run * al + ps;
    m_run = mn;
#pragma unroll
    for (int n = 0; n < 4; n++) o[n] *= al;

#pragma unroll
    for (int ks = 0; ks < 2; ks++) {
      uintx4 pu;
      pu.x = pk[ks * 4 + 0];
      pu.y = pk[ks * 4 + 1];
      pu.z = pk[ks * 4 + 2];
      pu.w = pk[ks * 4 + 3];
      const short8 pf = __builtin_bit_cast(short8, pu);
#pragma unroll
      for (int n = 0; n < 4; n++)
        o[n] = __builtin_amdgcn_mfma_f32_16x16x32_bf16(vfr[ks * 4 + n], pf, o[n], 0, 0, 0);
    }

    asm volatile("s_waitcnt vmcnt(0)");
    __syncthreads();
  }
#undef STAGE

  const float inv = 1.0f / l_run;
  bf16* yr = y + (size_t)(b * T + qrow) * 768 + h * 64;
#pragma unroll
  for (int n = 0; n < 4; n++) {
    uint2 pr;
    pr.x = cvtpk(o[n][0] * inv, o[n][1] * inv);
    pr.y = cvtpk(o[n][2] * inv, o[n][3] * inv);
    *(uint2*)(yr + n * 16 + g * 4) = pr;
  }
}

// ---------------- host side
extern "C" void kernel_launch(void* const* d_in, const int* in_sizes, int n_in,
                              void* d_out, int out_size, void* d_ws, size_t ws_size,
                              hipStream_t stream) {
  const float* x      = (const float*)d_in[0];
  const float* ln1_g  = (const float*)d_in[1];
  const float* ln1_b  = (const float*)d_in[2];
  const float* w_attn = (const float*)d_in[3];
  const float* b_attn = (const float*)d_in[4];
  const float* w_proj = (const float*)d_in[5];
  const float* b_proj = (const float*)d_in[6];
  const float* ln2_g  = (const float*)d_in[7];
  const float* ln2_b  = (const float*)d_in[8];
  const float* w_fc   = (const float*)d_in[9];
  const float* b_fc   = (const float*)d_in[10];
  const float* w_fc2  = (const float*)d_in[11];
  const float* b_fc2  = (const float*)d_in[12];
  float* out = (float*)d_out;

  const int M = 4096;  // B*T
  char* p = (char*)d_ws;
  bf16* wT_attn = (bf16*)p; p += (size_t)2304 * 768 * 2;
  bf16* wT_proj = (bf16*)p; p += (size_t)768 * 768 * 2;
  bf16* wT_fc   = (bf16*)p; p += (size_t)3072 * 768 * 2;
  bf16* wT_fc2  = (bf16*)p; p += (size_t)768 * 3072 * 2;
  bf16* h       = (bf16*)p; p += (size_t)M * 768 * 2;
  bf16* qkv     = (bf16*)p;
  bf16* yb      = (bf16*)(p + (size_t)M * 2304 * 2);
  bf16* act     = qkv;      p += (size_t)M * 2304 * 2 + (size_t)M * 768 * 2;
  float* x1     = (float*)p;
  bf16* VT      = (bf16*)p;  // aliases x1: VT dead before x1 is written

  // weights -> bf16 transposed
  kconvT<<<dim3(2304 / 32, 768 / 32), 256, 0, stream>>>(w_attn, wT_attn, 768, 2304);
  kconvT<<<dim3(768 / 32, 768 / 32), 256, 0, stream>>>(w_proj, wT_proj, 768, 768);
  kconvT<<<dim3(3072 / 32, 768 / 32), 256, 0, stream>>>(w_fc, wT_fc, 768, 3072);
  kconvT<<<dim3(768 / 32, 3072 / 32), 256, 0, stream>>>(w_fc2, wT_fc2, 3072, 768);

  // attention branch
  kln<<<M, 256, 0, stream>>>(x, ln1_g, ln1_b, h);
  kgemm<128, 0><<<dim3(18 * 32), 256, 0, stream>>>(
      h, wT_attn, b_attn, nullptr, qkv, nullptr, M, 2304, 768, 18);
  kxpose<<<dim3(32, 12, 2), 256, 0, stream>>>(qkv, VT);
  kattn<<<dim3(768), 256, 0, stream>>>(qkv, VT, yb);
  kgemm<64, 1><<<dim3(12 * 32), 256, 0, stream>>>(
      yb, wT_proj, b_proj, x, nullptr, x1, M, 768, 768, 12);

  // MLP branch
  kln<<<M, 256, 0, stream>>>(x1, ln2_g, ln2_b, h);
  kgemm<128, 2><<<dim3(24 * 32), 256, 0, stream>>>(
      h, wT_fc, b_fc, nullptr, act, nullptr, M, 3072, 768, 24);
  kgemm<64, 1><<<dim3(12 * 32), 256, 0, stream>>>(
      act, wT_fc2, b_fc2, x1, nullptr, out, M, 768, 3072, 12);
}